// Round 7
// baseline (7510.507 us; speedup 1.0000x reference)
//
#include <hip/hip_runtime.h>
#include <math.h>

typedef __attribute__((ext_vector_type(8))) short short8;
typedef __attribute__((ext_vector_type(4))) float f32x4;

#define MFMA16(a, b, c) __builtin_amdgcn_mfma_f32_16x16x32_bf16((a), (b), (c), 0, 0, 0)

__device__ __forceinline__ unsigned bfu(float f) {
    unsigned u = __float_as_uint(f);
    return (u + 0x7fffu + ((u >> 16) & 1u)) >> 16;   // RNE fp32->bf16
}

// GEMM swizzle: consecutive ids share by (A-row panel); XCD-chunk when nb%8==0.
__device__ __forceinline__ void swz_block(unsigned& bx, unsigned& by, unsigned& bz) {
    unsigned gx = gridDim.x, gy = gridDim.y, gz = gridDim.z;
    unsigned nb = gx * gy * gz;
    unsigned d = blockIdx.x + gx * (blockIdx.y + gy * blockIdx.z);
    if ((nb & 7u) == 0u) d = (d & 7u) * (nb >> 3) + (d >> 3);
    bx = d % gx;
    unsigned r = d / gx;
    by = r % gy;
    bz = r / gy;
}

// Conv swizzle: by-fastest — consecutive dispatch ids share bx (same x tile),
// so all o-groups reading one x panel are temporally co-resident (L2/L3 hit).
__device__ __forceinline__ void swz_conv(unsigned& bx, unsigned& by, unsigned& bz) {
    unsigned gx = gridDim.x, gy = gridDim.y, gz = gridDim.z;
    unsigned nb = gx * gy * gz;
    unsigned d = blockIdx.x + gx * (blockIdx.y + gy * blockIdx.z);
    if ((nb & 7u) == 0u) d = (d & 7u) * (nb >> 3) + (d >> 3);
    by = d % gy;
    unsigned r = d / gy;
    bx = r % gx;
    bz = r / gx;
}

// ---------------- constants ----------------
static constexpr int TT   = 1026;
static constexpr int T_S1 = 8216;
static constexpr int T_S2 = 49302;
static constexpr int T_S3 = 246515;
static constexpr int T_S4 = 986064;

static constexpr int NCH    = 8;
static constexpr int LC     = T_S4 / NCH;        // 123258
static constexpr int LE_MAX = LC + 8;

// workspace offsets (floats).
static constexpr size_t O_X0  = 0;
static constexpr size_t O_XQ  = 262144;
static constexpr size_t O_XU  = 524288;
static constexpr size_t O_Z   = 1049600;
static constexpr size_t O_HN  = 1574912;
static constexpr size_t O_QKV = 2100224;   // also: quant partials, up-convtr w'
static constexpr size_t O_AO  = 3676160;
static constexpr size_t O_FF  = 4201472;   // also: dc0 partial
static constexpr size_t O_COS = 6302720;
static constexpr size_t O_SIN = 6335552;
static constexpr size_t O_ZT  = 6368384;
static constexpr size_t O_ZC  = 6893696;
static constexpr size_t O_D0  = 7419008;
static constexpr size_t O_Z1  = 8469632;
static constexpr size_t O_V1  = 12676224;
static constexpr size_t O_PS1 = 16000000;  // s1/s2 convtr w', s1-conv3 partial
static constexpr size_t O_Z2  = 31553920;
static constexpr size_t O_V2  = 0;
static constexpr size_t O_Z3  = 0;
static constexpr size_t O_V3  = 31553920;
static constexpr size_t O_Z4C = 31553920;
static constexpr size_t O_VAC = 39442944;  // ends 43,387,456
static constexpr size_t O_WS4 = 43388928;  // stage-4 convtr w' (65,536)
static constexpr size_t O_WS3 = 44176256;  // stage-3 convtr w' (327,680)

static inline int cdiv(int a, int b) { return (a + b - 1) / b; }

// ---------------- partial reduce: y[i] += sum_z p[i + z*pstr] ----------------
__global__ __launch_bounds__(256) void addp_k(float* __restrict__ y,
    const float* __restrict__ p, unsigned long long pstr, int np, int n4)
{
    int i = blockIdx.x * 256 + threadIdx.x;
    if (i >= n4) return;
    float4 s = ((float4*)y)[i];
    for (int z = 0; z < np; z++) {
        float4 q = ((const float4*)(p + (size_t)z * pstr))[i];
        s.x += q.x; s.y += q.y; s.z += q.z; s.w += q.w;
    }
    ((float4*)y)[i] = s;
}

// ---------------- convtr weight reorder ----------------
// wp[(co*S+p)*Ci*2 + ci*2 + j] = w[(ci*Co + co)*2S + (1-j)*S + p]
__global__ __launch_bounds__(256) void wreorder_tr(const float* __restrict__ w,
    float* __restrict__ wp, int Ci, int Co, int S, int n)
{
    int i = blockIdx.x * 256 + threadIdx.x;
    if (i >= n) return;
    int o = i / (Ci * 2), r = i - o * (Ci * 2);
    int ci = r >> 1, j = r & 1;
    int co = o / S, p = o - co * S;
    wp[i] = w[((size_t)ci * Co + co) * (2 * S) + (1 - j) * S + p];
}

// ---------------- elementwise / small fp32 kernels ----------------
__global__ __launch_bounds__(256) void embed_k(const float* __restrict__ lat,
    const float* __restrict__ sd, const float* __restrict__ mn, float* __restrict__ y)
{
    int i = blockIdx.x * 256 + threadIdx.x;
    if (i >= 512 * 512) return;
    int c = i >> 9;
    y[i] = lat[i] * sd[c] + mn[c];
}

__global__ __launch_bounds__(256) void rope_tables(float* __restrict__ cs, float* __restrict__ sn)
{
    int idx = blockIdx.x * 256 + threadIdx.x;
    if (idx >= TT * 32) return;
    int i = idx & 31;
    int t = idx >> 5;
    float fr = expf(-(float)i * (logf(10000.f) / 32.f));
    float ang = (float)t * fr;
    cs[idx] = cosf(ang);
    sn[idx] = sinf(ang);
}

__global__ __launch_bounds__(256) void rope_apply(float* __restrict__ qkv,
    const float* __restrict__ cs, const float* __restrict__ sn)
{
    int idx = blockIdx.x * 256 + threadIdx.x;
    if (idx >= TT * 8 * 32) return;
    int i = idx & 31;
    int h = (idx >> 5) & 7;
    int t = idx >> 8;
    float c = cs[t * 32 + i], s = sn[t * 32 + i];
    size_t base = (size_t)t * 1536 + h * 64 + 2 * i;
    float re = qkv[base], im = qkv[base + 1];
    qkv[base]     = re * c - im * s;
    qkv[base + 1] = re * s + im * c;
    base += 512;
    re = qkv[base]; im = qkv[base + 1];
    qkv[base]     = re * c - im * s;
    qkv[base + 1] = re * s + im * c;
}

__global__ __launch_bounds__(256) void transpose_k(const float* __restrict__ in,
    float* __restrict__ out, int R, int C)
{
    __shared__ float tile[32][33];
    int c0 = blockIdx.x * 32, r0 = blockIdx.y * 32;
    int tx = threadIdx.x & 31, ty = threadIdx.x >> 5;
    for (int dy = ty; dy < 32; dy += 8) {
        int r = r0 + dy, c = c0 + tx;
        tile[dy][tx] = (r < R && c < C) ? in[(size_t)r * C + c] : 0.f;
    }
    __syncthreads();
    for (int dy = ty; dy < 32; dy += 8) {
        int c = c0 + dy, r = r0 + tx;
        if (c < C && r < R) out[(size_t)c * R + r] = tile[tx][dy];
    }
}

__global__ __launch_bounds__(256) void ln_kernel(const float* __restrict__ x,
    const float* __restrict__ w, const float* __restrict__ b, float* __restrict__ y)
{
    int t = blockIdx.x, tid = threadIdx.x;
    const float* xr = x + (size_t)t * 512;
    float v0 = xr[tid], v1 = xr[tid + 256];
    float s = v0 + v1, q = v0 * v0 + v1 * v1;
    for (int off = 32; off; off >>= 1) {
        s += __shfl_down(s, off);
        q += __shfl_down(q, off);
    }
    __shared__ float ss[4], qq[4], mb[2];
    int wid = tid >> 6, lane = tid & 63;
    if (lane == 0) { ss[wid] = s; qq[wid] = q; }
    __syncthreads();
    if (tid == 0) {
        float S = ss[0] + ss[1] + ss[2] + ss[3];
        float Q = qq[0] + qq[1] + qq[2] + qq[3];
        float m = S * (1.f / 512.f);
        float var = Q * (1.f / 512.f) - m * m;
        mb[0] = m;
        mb[1] = rsqrtf(var + 1e-5f);
    }
    __syncthreads();
    float m = mb[0], inv = mb[1];
    y[(size_t)t * 512 + tid]       = (v0 - m) * inv * w[tid] + b[tid];
    y[(size_t)t * 512 + tid + 256] = (v1 - m) * inv * w[tid + 256] + b[tid + 256];
}

__global__ __launch_bounds__(256) void attn_kernel(const float* __restrict__ qkv,
    float* __restrict__ o)
{
    int t = blockIdx.x, h = blockIdx.y, tid = threadIdx.x;
    __shared__ float sq[64];
    __shared__ float sp[256];
    __shared__ float red[256];
    __shared__ float pacc[4][64];
    int klo = t - 249; if (klo < 0) klo = 0;
    int kc = t - klo + 1;
    if (tid < 64) sq[tid] = qkv[(size_t)t * 1536 + h * 64 + tid];
    __syncthreads();
    float sval = -3.0e38f;
    if (tid < kc) {
        const float* kr = qkv + (size_t)(klo + tid) * 1536 + 512 + h * 64;
        float d = 0.f;
#pragma unroll 8
        for (int i = 0; i < 64; i++) d += sq[i] * kr[i];
        sval = d * 0.125f;
    }
    red[tid] = sval;
    __syncthreads();
    for (int s2 = 128; s2 > 0; s2 >>= 1) {
        if (tid < s2) red[tid] = fmaxf(red[tid], red[tid + s2]);
        __syncthreads();
    }
    float m = red[0];
    __syncthreads();
    float p = (tid < kc) ? __expf(sval - m) : 0.f;
    sp[tid] = p;
    red[tid] = p;
    __syncthreads();
    for (int s2 = 128; s2 > 0; s2 >>= 1) {
        if (tid < s2) red[tid] += red[tid + s2];
        __syncthreads();
    }
    float inv = 1.f / red[0];
    int d = tid & 63, g = tid >> 6;
    float a = 0.f;
#pragma unroll 4
    for (int kk = g; kk < kc; kk += 4)
        a += sp[kk] * qkv[(size_t)(klo + kk) * 1536 + 1024 + h * 64 + d];
    pacc[g][d] = a;
    __syncthreads();
    if (tid < 64) {
        float r = (pacc[0][tid] + pacc[1][tid] + pacc[2][tid] + pacc[3][tid]) * inv;
        o[(size_t)t * 512 + h * 64 + tid] = r;
    }
}

// ---------------- MFMA GEMM: C[m,n] = sum_k A[m,k]*Wt[n,k] ----------------
template <int EPI>
__global__ __launch_bounds__(256, 3) void mfma_gemm(const float* __restrict__ A,
    const float* __restrict__ Wt, const float* __restrict__ bias,
    const float* __restrict__ ls, float* __restrict__ C, int M, int N, int K)
{
    constexpr int STR = 72;   // u16 stride (144B, 16B-aligned)
    __shared__ unsigned short sA[128 * STR];
    __shared__ unsigned short sB[128 * STR];
    int tid = threadIdx.x;
    unsigned bxs, bys, bzs; swz_block(bxs, bys, bzs);
    int m0 = bys * 128, n0 = bxs * 128;
    int w = tid >> 6, lane = tid & 63;
    int wm = (w >> 1) * 64, wn = (w & 1) * 64;
    int row15 = lane & 15, q8 = (lane >> 4) * 8;
    int rb = tid >> 3;            // base staging row
    int sg = (tid & 7) * 8;       // k-segment within row
    f32x4 acc[4][4] = {};
    float4 av[8], bv[8];
    const float4 z4 = make_float4(0.f, 0.f, 0.f, 0.f);

    auto prefetch = [&](int k0) {
#pragma unroll
        for (int it = 0; it < 4; it++) {
            int r = rb + it * 32;
            int gm = m0 + r;
            if (gm < M) {
                const float4* p = (const float4*)(A + (size_t)gm * K + k0 + sg);
                av[2 * it] = p[0]; av[2 * it + 1] = p[1];
            } else { av[2 * it] = z4; av[2 * it + 1] = z4; }
            int gn = n0 + r;
            if (gn < N) {
                const float4* p = (const float4*)(Wt + (size_t)gn * K + k0 + sg);
                bv[2 * it] = p[0]; bv[2 * it + 1] = p[1];
            } else { bv[2 * it] = z4; bv[2 * it + 1] = z4; }
        }
    };

    prefetch(0);
    for (int k0 = 0; k0 < K; k0 += 64) {
        __syncthreads();
        // commit to LDS
#pragma unroll
        for (int it = 0; it < 4; it++) {
            int r = rb + it * 32;
            unsigned* d = (unsigned*)&sA[r * STR + sg];
            float4 f0 = av[2 * it], f1 = av[2 * it + 1];
            d[0] = bfu(f0.x) | (bfu(f0.y) << 16); d[1] = bfu(f0.z) | (bfu(f0.w) << 16);
            d[2] = bfu(f1.x) | (bfu(f1.y) << 16); d[3] = bfu(f1.z) | (bfu(f1.w) << 16);
            d = (unsigned*)&sB[r * STR + sg];
            f0 = bv[2 * it]; f1 = bv[2 * it + 1];
            d[0] = bfu(f0.x) | (bfu(f0.y) << 16); d[1] = bfu(f0.z) | (bfu(f0.w) << 16);
            d[2] = bfu(f1.x) | (bfu(f1.y) << 16); d[3] = bfu(f1.z) | (bfu(f1.w) << 16);
        }
        __syncthreads();
        if (k0 + 64 < K) prefetch(k0 + 64);
#pragma unroll
        for (int kk = 0; kk < 64; kk += 32) {
            short8 af[4], bf[4];
#pragma unroll
            for (int f = 0; f < 4; f++) {
                af[f] = *(const short8*)&sA[(wm + f * 16 + row15) * STR + kk + q8];
                bf[f] = *(const short8*)&sB[(wn + f * 16 + row15) * STR + kk + q8];
            }
#pragma unroll
            for (int i = 0; i < 4; i++)
#pragma unroll
                for (int j = 0; j < 4; j++)
                    acc[i][j] = MFMA16(af[i], bf[j], acc[i][j]);
        }
    }
    int rq = (lane >> 4) * 4;
#pragma unroll
    for (int i = 0; i < 4; i++) {
#pragma unroll
        for (int r = 0; r < 4; r++) {
            int m = m0 + wm + i * 16 + rq + r;
            if (m >= M) continue;
#pragma unroll
            for (int j = 0; j < 4; j++) {
                int n = n0 + wn + j * 16 + row15;
                float v = acc[i][j][r] + bias[n];
                size_t idx = (size_t)m * N + n;
                if (EPI == 0) C[idx] = v;
                else if (EPI == 1) C[idx] = 0.5f * v * (1.f + erff(v * 0.70710678118654752f));
                else C[idx] += ls[n] * v;
            }
        }
    }
}

// ---------------- MFMA causal conv (K taps) ----------------
// y[o, t] = b[o] + sum_{ci,j} w[o,ci,j] * f(x[ci, t-(K-1)+j])
// Block tile 64o x 128t; ci-chunks of 32. Two-phase staging, cross-chunk pipeline.
// SHF=0: plain epilogue (opt. ci-split partials via PART).
// SHF=S: transposed-conv epilogue via LDS transpose in TWO 64-col halves; the
//        transpose buffer ALIASES the (dead) staging LDS, keeping LDS ~20 KB.
template <int K, int SHF, bool ELU_IN, bool ACC, bool PART>
__global__ __launch_bounds__(256, 4) void mfma_conv(
    const float* __restrict__ x, const float* __restrict__ w,
    const float* __restrict__ bias, float* __restrict__ y, float* __restrict__ part,
    unsigned long long pstr,
    int Ci, int Co, int x_str, int Tx, int x_t0, int Ty, int y_t0, int to_lo, int to_hi,
    int sh_lo, int sh_hi, int nz)
{
    constexpr int TL = 128 + K - 1;
    constexpr int SX = 40;  // u16 stride (80B)
    constexpr int SW = 40;
    constexpr int NX = (32 * TL + 255) / 256;  // scalar x elems per thread
    constexpr int NW4 = 2 * K;                 // float4 w loads per thread
    constexpr int SXB = TL * SX;               // u16 counts
    constexpr int SWB = K * 64 * SW;
    static_assert(SHF == 0 || (SXB + SWB) * 2 >= 64 * 66 * 4, "ldsT alias too big");
    __shared__ __align__(16) unsigned short shm[SXB + SWB];
    unsigned short* sX = shm;
    unsigned short* sW = shm + SXB;
    float* ldsT = (float*)shm;                 // SHF>0 only; used after last MFMA
    int tid = threadIdx.x;
    unsigned bxs, bys, bzs; swz_conv(bxs, bys, bzs);
    int co0 = bys * 64;                 // o-row base
    int t_base = to_lo + bxs * 128;
    int zi = (int)bzs;
    int cpz = (Ci / 32) / nz;
    int ci_b = zi * cpz * 32, ci_e = ci_b + cpz * 32;
    int w_id = tid >> 6, lane = tid & 63;
    int wm = (w_id >> 1) * 32, wn = (w_id & 1) * 64;
    int row15 = lane & 15, q8 = (lane >> 4) * 8;
    f32x4 acc[2][4] = {};
    float xv[NX];
    float4 wv4[NW4];
    const float4 z4 = make_float4(0.f, 0.f, 0.f, 0.f);

    auto prefetch = [&](int ci0) {
#pragma unroll
        for (int it = 0; it < NX; it++) {
            int i = tid + it * 256;
            float v = 0.f;
            if (i < 32 * TL) {
                int ci = i / TL, tl = i - ci * TL;
                int gl = t_base - (K - 1) + tl - x_t0;
                if (gl >= 0 && gl < Tx) v = x[(size_t)(ci0 + ci) * x_str + gl];
            }
            xv[it] = v;
        }
#pragma unroll
        for (int it = 0; it < NW4; it++) {
            int i4 = tid + it * 256;
            int co = i4 / (8 * K), r4 = i4 - co * (8 * K);
            wv4[it] = (co0 + co < Co)
                ? *(const float4*)(w + ((size_t)(co0 + co) * Ci + ci0) * K + r4 * 4)
                : z4;
        }
    };
    auto commit = [&]() {
#pragma unroll
        for (int it = 0; it < NX; it++) {
            int i = tid + it * 256;
            if (i < 32 * TL) {
                int ci = i / TL, tl = i - ci * TL;
                float v = xv[it];
                if (ELU_IN) v = v > 0.f ? v : __expf(v) - 1.f;
                sX[tl * SX + ci] = (unsigned short)bfu(v);
            }
        }
#pragma unroll
        for (int it = 0; it < NW4; it++) {
            int i4 = tid + it * 256;
            int co = i4 / (8 * K), r4 = i4 - co * (8 * K);
            float4 f = wv4[it];
#pragma unroll
            for (int e = 0; e < 4; e++) {
                int k = r4 * 4 + e;
                int ci = k / K, j = k - ci * K;
                float fv = (e == 0) ? f.x : (e == 1) ? f.y : (e == 2) ? f.z : f.w;
                sW[(j * 64 + co) * SW + ci] = (unsigned short)bfu(fv);
            }
        }
    };

    prefetch(ci_b);
    for (int ci0 = ci_b; ci0 < ci_e; ci0 += 32) {
        __syncthreads();
        commit();
        __syncthreads();
        if (ci0 + 32 < ci_e) prefetch(ci0 + 32);   // loads fly over the MFMAs below
#pragma unroll
        for (int j = 0; j < K; j++) {
            short8 af[2], bf[4];
#pragma unroll
            for (int f = 0; f < 2; f++)
                af[f] = *(const short8*)&sW[(j * 64 + wm + f * 16 + row15) * SW + q8];
#pragma unroll
            for (int f = 0; f < 4; f++)
                bf[f] = *(const short8*)&sX[(wn + f * 16 + row15 + j) * SX + q8];
#pragma unroll
            for (int i = 0; i < 2; i++)
#pragma unroll
                for (int f = 0; f < 4; f++)
                    acc[i][f] = MFMA16(af[i], bf[f], acc[i][f]);
        }
    }
    int rq = (lane >> 4) * 4;
    if constexpr (SHF > 0) {
        // two halves of 64 t-cols; ldsT aliases the dead staging LDS
        int co_lo = co0 / SHF;
        int cnt = (co0 + 63) / SHF - co_lo + 1;
        int tot = cnt * 64 * SHF;
#pragma unroll
        for (int h = 0; h < 2; h++) {
            __syncthreads();
            if (wn == h * 64) {
#pragma unroll
                for (int i = 0; i < 2; i++) {
#pragma unroll
                    for (int r = 0; r < 4; r++) {
                        int ol = wm + i * 16 + rq + r;
                        float b = bias[(co0 + ol) / SHF];
#pragma unroll
                        for (int f = 0; f < 4; f++)
                            ldsT[ol * 66 + f * 16 + row15] = acc[i][f][r] + b;
                    }
                }
            }
            __syncthreads();
            for (int e = tid; e < tot; e += 256) {
                int cr = e / (64 * SHF), u = e - cr * (64 * SHF);
                int tr = u / SHF, p = u - tr * SHF;
                int co = co_lo + cr;
                int o = co * SHF + p - co0;
                int to = (t_base + h * 64 + tr) * SHF + p;
                if (o >= 0 && o < 64 && to >= sh_lo && to < sh_hi)
                    y[(size_t)co * Ty + (to - y_t0)] = ldsT[o * 66 + tr];
            }
        }
    } else {
#pragma unroll
        for (int i = 0; i < 2; i++) {
#pragma unroll
            for (int r = 0; r < 4; r++) {
                int co = co0 + wm + i * 16 + rq + r;
                if (co >= Co) continue;
                float b = bias[co];
#pragma unroll
                for (int f = 0; f < 4; f++) {
                    int t = t_base + wn + f * 16 + row15;
                    if (t < to_hi) {
                        size_t idx = (size_t)co * Ty + (t - y_t0);
                        if (PART && zi > 0) {
                            part[(size_t)(zi - 1) * pstr + idx] = acc[i][f][r];
                        } else {
                            float v = acc[i][f][r] + b;
                            if (ACC) y[idx] += v; else y[idx] = v;
                        }
                    }
                }
            }
        }
    }
}

// ---------------- final conv (Co=1), fp32 ----------------
__global__ __launch_bounds__(256) void conv7_out_chunk(const float* __restrict__ z4c,
    const float* __restrict__ w, const float* __restrict__ bias,
    float* __restrict__ out, int ext0, int t0, int cnt)
{
    __shared__ float ws_w[64 * 7];
    int tl = blockIdx.x * 256 + threadIdx.x;
    for (int i = threadIdx.x; i < 448; i += 256) ws_w[i] = w[i];
    __syncthreads();
    if (tl >= cnt) return;
    int t = t0 + tl;
    float acc = bias[0];
    for (int ci = 0; ci < 64; ci++) {
        const float* xr = z4c + (size_t)ci * LE_MAX;
#pragma unroll
        for (int j = 0; j < 7; j++) {
            int tg = t - 6 + j;
            float v = 0.f;
            if (tg >= 0) {
                float z = xr[tg - ext0];
                v = z > 0.f ? z : __expf(z) - 1.f;
            }
            acc += ws_w[ci * 7 + j] * v;
        }
    }
    out[t] = acc;
}

// ---------------- host helpers ----------------
template <int K, bool ELU_IN, bool ACC, bool PART>
static void conv_launch(const float* x, const float* w, const float* b, float* y,
    float* part, unsigned long long pstr,
    int Ci, int Co, int x_str, int Tx, int x_t0, int Ty, int y_t0, int to_lo, int to_hi,
    int nz, hipStream_t stream)
{
    dim3 g(cdiv(to_hi - to_lo, 128), cdiv(Co, 64), nz);
    mfma_conv<K, 0, ELU_IN, ACC, PART><<<g, 256, 0, stream>>>(x, w, b, y, part, pstr,
        Ci, Co, x_str, Tx, x_t0, Ty, y_t0, to_lo, to_hi, 0, 0, nz);
}

// transposed conv as K=2 conv over Co*S channels with shuffled epilogue.
template <int S, bool ELU_IN>
static void convtr2_launch(const float* x, const float* wp, const float* b, float* y,
    int Ci, int Co, int Ti, int Ty, int y_t0, int to_lo, int to_hi, hipStream_t stream)
{
    int q_lo = to_lo / S;
    int q_hi = cdiv(to_hi, S);
    dim3 g(cdiv(q_hi - q_lo, 128), (Co * S) / 64, 1);
    mfma_conv<2, S, ELU_IN, false, false><<<g, 256, 0, stream>>>(x, wp, b, y, nullptr, 0,
        Ci, Co * S, Ti, Ti, 0, Ty, y_t0, q_lo, q_hi, to_lo, to_hi, 1);
}

extern "C" void kernel_launch(void* const* d_in, const int* in_sizes, int n_in,
                              void* d_out, int out_size, void* d_ws, size_t ws_size,
                              hipStream_t stream)
{
    const float* latent  = (const float*)d_in[0];
    const float* emb_std = (const float*)d_in[1];
    const float* emb_mean= (const float*)d_in[2];
    const float* quant_w = (const float*)d_in[3];
    const float* quant_b = (const float*)d_in[4];
    const float* up_w    = (const float*)d_in[5];
    const float* up_b    = (const float*)d_in[6];
    const float* n1w     = (const float*)d_in[7];
    const float* n1b     = (const float*)d_in[8];
    const float* ipw     = (const float*)d_in[9];
    const float* ipb     = (const float*)d_in[10];
    const float* opw     = (const float*)d_in[11];
    const float* opb     = (const float*)d_in[12];
    const float* ls1     = (const float*)d_in[13];
    const float* n2w     = (const float*)d_in[14];
    const float* n2b     = (const float*)d_in[15];
    const float* l1w     = (const float*)d_in[16];
    const float* l1b     = (const float*)d_in[17];
    const float* l2w     = (const float*)d_in[18];
    const float* l2b     = (const float*)d_in[19];
    const float* ls2     = (const float*)d_in[20];
    const float* tproj_w = (const float*)d_in[21];
    const float* tproj_b = (const float*)d_in[22];
    const float* dc0_w   = (const float*)d_in[23];
    const float* dc0_b   = (const float*)d_in[24];
    const float* df_w    = (const float*)d_in[49];
    const float* df_b    = (const float*)d_in[50];

    float* W = (float*)d_ws;
    float* OUT = (float*)d_out;

    // ---- frontend ----
    embed_k<<<cdiv(512 * 512, 256), 256, 0, stream>>>(latent, emb_std, emb_mean, W + O_X0);
    conv_launch<1, false, false, true>(W + O_X0, quant_w, quant_b, W + O_XQ,
        W + O_QKV, 262144ULL, 512, 512, 512, 512, 0, 512, 0, 0, 512, 4, stream);
    addp_k<<<cdiv(262144 / 4, 256), 256, 0, stream>>>(W + O_XQ, W + O_QKV, 262144ULL, 3, 262144 / 4);
    wreorder_tr<<<cdiv(1048576, 256), 256, 0, stream>>>(up_w, W + O_QKV, 512, 512, 2, 1048576);
    convtr2_launch<2, false>(W + O_XQ, W + O_QKV, up_b, W + O_XU,
        512, 512, 512, TT, 0, 0, TT, stream);
    transpose_k<<<dim3(cdiv(TT, 32), cdiv(512, 32)), 256, 0, stream>>>(W + O_XU, W + O_Z, 512, TT);
    rope_tables<<<cdiv(TT * 32, 256), 256, 0, stream>>>(W + O_COS, W + O_SIN);

    // ---- transformer ----
    for (int l = 0; l < 8; l++) {
        ln_kernel<<<TT, 256, 0, stream>>>(W + O_Z, n1w + l * 512, n1b + l * 512, W + O_HN);
        mfma_gemm<0><<<dim3(1536 / 128, cdiv(TT, 128)), 256, 0, stream>>>(
            W + O_HN, ipw + (size_t)l * 1536 * 512, ipb + l * 1536, nullptr, W + O_QKV, TT, 1536, 512);
        rope_apply<<<cdiv(TT * 8 * 32, 256), 256, 0, stream>>>(W + O_QKV, W + O_COS, W + O_SIN);
        attn_kernel<<<dim3(TT, 8), 256, 0, stream>>>(W + O_QKV, W + O_AO);
        mfma_gemm<2><<<dim3(512 / 128, cdiv(TT, 128)), 256, 0, stream>>>(
            W + O_AO, opw + (size_t)l * 512 * 512, opb + l * 512, ls1 + l * 512, W + O_Z, TT, 512, 512);
        ln_kernel<<<TT, 256, 0, stream>>>(W + O_Z, n2w + l * 512, n2b + l * 512, W + O_HN);
        mfma_gemm<1><<<dim3(2048 / 128, cdiv(TT, 128)), 256, 0, stream>>>(
            W + O_HN, l1w + (size_t)l * 2048 * 512, l1b + l * 2048, nullptr, W + O_FF, TT, 2048, 512);
        mfma_gemm<2><<<dim3(512 / 128, cdiv(TT, 128)), 256, 0, stream>>>(
            W + O_FF, l2w + (size_t)l * 512 * 2048, l2b + l * 512, ls2 + l * 512, W + O_Z, TT, 512, 2048);
    }

    // ---- back to conv domain ----
    mfma_gemm<0><<<dim3(512 / 128, cdiv(TT, 128)), 256, 0, stream>>>(
        W + O_Z, tproj_w, tproj_b, nullptr, W + O_ZT, TT, 512, 512);
    transpose_k<<<dim3(cdiv(512, 32), cdiv(TT, 32)), 256, 0, stream>>>(W + O_ZT, W + O_ZC, TT, 512);
    conv_launch<7, false, false, true>(W + O_ZC, dc0_w, dc0_b, W + O_D0,
        W + O_FF, 1050624ULL, 512, 1024, TT, TT, 0, TT, 0, 0, TT, 2, stream);
    addp_k<<<cdiv(1050624 / 4, 256), 256, 0, stream>>>(W + O_D0, W + O_FF, 1050624ULL, 1, 1050624 / 4);

    // ---- stage 1: 1024 -> 512, s=8 ----
    {
        const float* tw = (const float*)d_in[25]; const float* tb = (const float*)d_in[26];
        const float* raw = (const float*)d_in[27]; const float* rab = (const float*)d_in[28];
        const float* rbw = (const float*)d_in[29]; const float* rbb = (const float*)d_in[30];
        wreorder_tr<<<cdiv(8388608, 256), 256, 0, stream>>>(tw, W + O_PS1, 1024, 512, 8, 8388608);
        convtr2_launch<8, true>(W + O_D0, W + O_PS1, tb, W + O_Z1,
            1024, 512, TT, T_S1, 0, 0, T_S1, stream);
        conv_launch<3, true, false, true>(W + O_Z1, raw, rab, W + O_V1,
            W + O_PS1, 2103296ULL, 512, 256, T_S1, T_S1, 0, T_S1, 0, 0, T_S1, 2, stream);
        addp_k<<<cdiv(2103296 / 4, 256), 256, 0, stream>>>(W + O_V1, W + O_PS1, 2103296ULL, 1, 2103296 / 4);
        conv_launch<1, true, true, false>(W + O_V1, rbw, rbb, W + O_Z1,
            nullptr, 0ULL, 256, 512, T_S1, T_S1, 0, T_S1, 0, 0, T_S1, 1, stream);
    }
    // ---- stage 2: 512 -> 256, s=6 ----
    {
        const float* tw = (const float*)d_in[31]; const float* tb = (const float*)d_in[32];
        const float* raw = (const float*)d_in[33]; const float* rab = (const float*)d_in[34];
        const float* rbw = (const float*)d_in[35]; const float* rbb = (const float*)d_in[36];
        wreorder_tr<<<cdiv(1572864, 256), 256, 0, stream>>>(tw, W + O_PS1, 512, 256, 6, 1572864);
        convtr2_launch<6, true>(W + O_Z1, W + O_PS1, tb, W + O_Z2,
            512, 256, T_S1, T_S2, 0, 0, T_S2, stream);
        conv_launch<3, true, false, false>(W + O_Z2, raw, rab, W + O_V2,
            nullptr, 0ULL, 256, 128, T_S2, T_S2, 0, T_S2, 0, 0, T_S2, 1, stream);
        conv_launch<1, true, true, false>(W + O_V2, rbw, rbb, W + O_Z2,
            nullptr, 0ULL, 128, 256, T_S2, T_S2, 0, T_S2, 0, 0, T_S2, 1, stream);
    }
    // ---- stage 3: 256 -> 128, s=5 ----
    {
        const float* tw = (const float*)d_in[37]; const float* tb = (const float*)d_in[38];
        const float* raw = (const float*)d_in[39]; const float* rab = (const float*)d_in[40];
        const float* rbw = (const float*)d_in[41]; const float* rbb = (const float*)d_in[42];
        wreorder_tr<<<cdiv(327680, 256), 256, 0, stream>>>(tw, W + O_WS3, 256, 128, 5, 327680);
        convtr2_launch<5, true>(W + O_Z2, W + O_WS3, tb, W + O_Z3,
            256, 128, T_S2, T_S3, 0, 0, T_S3, stream);
        conv_launch<3, true, false, false>(W + O_Z3, raw, rab, W + O_V3,
            nullptr, 0ULL, 128, 64, T_S3, T_S3, 0, T_S3, 0, 0, T_S3, 1, stream);
        conv_launch<1, true, true, false>(W + O_V3, rbw, rbb, W + O_Z3,
            nullptr, 0ULL, 64, 128, T_S3, T_S3, 0, T_S3, 0, 0, T_S3, 1, stream);
    }
    // ---- stage 4 (128 -> 64, s=4) + final conv: temporally chunked ----
    {
        const float* tw = (const float*)d_in[43]; const float* tb = (const float*)d_in[44];
        const float* raw = (const float*)d_in[45]; const float* rab = (const float*)d_in[46];
        const float* rbw = (const float*)d_in[47]; const float* rbb = (const float*)d_in[48];
        wreorder_tr<<<cdiv(65536, 256), 256, 0, stream>>>(tw, W + O_WS4, 128, 64, 4, 65536);
        for (int c = 0; c < NCH; c++) {
            int t0 = c * LC;
            int ext0 = (c == 0) ? 0 : t0 - 8;
            int Le = t0 + LC - ext0;
            int vlo = (c == 0) ? 0 : ext0 + 2;
            convtr2_launch<4, true>(W + O_Z3, W + O_WS4, tb, W + O_Z4C,
                128, 64, T_S3, LE_MAX, ext0, ext0, ext0 + Le, stream);
            conv_launch<3, true, false, false>(W + O_Z4C, raw, rab, W + O_VAC,
                nullptr, 0ULL, 64, 32, LE_MAX, Le, ext0, LE_MAX, ext0, vlo, ext0 + Le, 1, stream);
            conv_launch<1, true, true, false>(W + O_VAC, rbw, rbb, W + O_Z4C,
                nullptr, 0ULL, 32, 64, LE_MAX, Le, ext0, LE_MAX, ext0, vlo, ext0 + Le, 1, stream);
            conv7_out_chunk<<<dim3(cdiv(LC, 256), 1), 256, 0, stream>>>(
                W + O_Z4C, df_w, df_b, OUT, ext0, t0, LC);
        }
    }
}

// Round 8
// 6935.619 us; speedup vs baseline: 1.0829x; 1.0829x over previous
//
#include <hip/hip_runtime.h>
#include <math.h>

typedef __attribute__((ext_vector_type(8))) short short8;
typedef __attribute__((ext_vector_type(4))) float f32x4;

#define MFMA16(a, b, c) __builtin_amdgcn_mfma_f32_16x16x32_bf16((a), (b), (c), 0, 0, 0)

__device__ __forceinline__ unsigned bfu(float f) {
    unsigned u = __float_as_uint(f);
    return (u + 0x7fffu + ((u >> 16) & 1u)) >> 16;   // RNE fp32->bf16
}

// Bijective XCD chunking for ANY nb (m204 variant): hardware assigns XCD = d%8
// (round-robin); remap so each XCD owns a CONTIGUOUS logical range.
__device__ __forceinline__ unsigned xcd_chunk(unsigned d, unsigned nb) {
    unsigned q = nb >> 3, r = nb & 7u;
    unsigned x = d & 7u, i = d >> 3;
    return (x < r) ? x * (q + 1) + i : r * (q + 1) + (x - r) * q + i;
}

// GEMM swizzle: bx-fastest (consecutive logical ids share by = A-row panel).
__device__ __forceinline__ void swz_block(unsigned& bx, unsigned& by, unsigned& bz) {
    unsigned gx = gridDim.x, gy = gridDim.y, gz = gridDim.z;
    unsigned nb = gx * gy * gz;
    unsigned d = xcd_chunk(blockIdx.x + gx * (blockIdx.y + gy * blockIdx.z), nb);
    bx = d % gx;
    unsigned r = d / gx;
    by = r % gy;
    bz = r / gy;
}

// Conv swizzle: by-fastest (consecutive logical ids share bx = x tile); with
// xcd_chunk, all gy sharers of one x tile land on the SAME XCD's L2.
__device__ __forceinline__ void swz_conv(unsigned& bx, unsigned& by, unsigned& bz) {
    unsigned gx = gridDim.x, gy = gridDim.y, gz = gridDim.z;
    unsigned nb = gx * gy * gz;
    unsigned d = xcd_chunk(blockIdx.x + gx * (blockIdx.y + gy * blockIdx.z), nb);
    by = d % gy;
    unsigned r = d / gy;
    bx = r % gx;
    bz = r / gx;
}

// ---------------- constants ----------------
static constexpr int TT   = 1026;
static constexpr int T_S1 = 8216;
static constexpr int T_S2 = 49302;
static constexpr int T_S3 = 246515;
static constexpr int T_S4 = 986064;

static constexpr int NCH    = 8;
static constexpr int LC     = T_S4 / NCH;        // 123258
static constexpr int LE_MAX = LC + 8;

// workspace offsets (floats).
static constexpr size_t O_X0  = 0;
static constexpr size_t O_XQ  = 262144;
static constexpr size_t O_XU  = 524288;
static constexpr size_t O_Z   = 1049600;
static constexpr size_t O_HN  = 1574912;
static constexpr size_t O_QKV = 2100224;   // also: quant partials, up-convtr w'
static constexpr size_t O_AO  = 3676160;
static constexpr size_t O_FF  = 4201472;   // also: dc0 partial
static constexpr size_t O_COS = 6302720;
static constexpr size_t O_SIN = 6335552;
static constexpr size_t O_ZT  = 6368384;
static constexpr size_t O_ZC  = 6893696;
static constexpr size_t O_D0  = 7419008;
static constexpr size_t O_Z1  = 8469632;
static constexpr size_t O_V1  = 12676224;
static constexpr size_t O_PS1 = 16000000;  // s1/s2 convtr w', s1-conv3 partial
static constexpr size_t O_Z2  = 31553920;
static constexpr size_t O_V2  = 0;
static constexpr size_t O_Z3  = 0;
static constexpr size_t O_V3  = 31553920;
static constexpr size_t O_Z4C = 31553920;
static constexpr size_t O_VAC = 39442944;  // ends 43,387,456
static constexpr size_t O_WS4 = 43388928;  // stage-4 convtr w' (65,536)
static constexpr size_t O_WS3 = 44176256;  // stage-3 convtr w' (327,680)

static inline int cdiv(int a, int b) { return (a + b - 1) / b; }

// ---------------- partial reduce: y[i] += sum_z p[i + z*pstr] ----------------
__global__ __launch_bounds__(256) void addp_k(float* __restrict__ y,
    const float* __restrict__ p, unsigned long long pstr, int np, int n4)
{
    int i = blockIdx.x * 256 + threadIdx.x;
    if (i >= n4) return;
    float4 s = ((float4*)y)[i];
    for (int z = 0; z < np; z++) {
        float4 q = ((const float4*)(p + (size_t)z * pstr))[i];
        s.x += q.x; s.y += q.y; s.z += q.z; s.w += q.w;
    }
    ((float4*)y)[i] = s;
}

// ---------------- convtr weight reorder ----------------
// wp[(co*S+p)*Ci*2 + ci*2 + j] = w[(ci*Co + co)*2S + (1-j)*S + p]
__global__ __launch_bounds__(256) void wreorder_tr(const float* __restrict__ w,
    float* __restrict__ wp, int Ci, int Co, int S, int n)
{
    int i = blockIdx.x * 256 + threadIdx.x;
    if (i >= n) return;
    int o = i / (Ci * 2), r = i - o * (Ci * 2);
    int ci = r >> 1, j = r & 1;
    int co = o / S, p = o - co * S;
    wp[i] = w[((size_t)ci * Co + co) * (2 * S) + (1 - j) * S + p];
}

// ---------------- elementwise / small fp32 kernels ----------------
__global__ __launch_bounds__(256) void embed_k(const float* __restrict__ lat,
    const float* __restrict__ sd, const float* __restrict__ mn, float* __restrict__ y)
{
    int i = blockIdx.x * 256 + threadIdx.x;
    if (i >= 512 * 512) return;
    int c = i >> 9;
    y[i] = lat[i] * sd[c] + mn[c];
}

__global__ __launch_bounds__(256) void rope_tables(float* __restrict__ cs, float* __restrict__ sn)
{
    int idx = blockIdx.x * 256 + threadIdx.x;
    if (idx >= TT * 32) return;
    int i = idx & 31;
    int t = idx >> 5;
    float fr = expf(-(float)i * (logf(10000.f) / 32.f));
    float ang = (float)t * fr;
    cs[idx] = cosf(ang);
    sn[idx] = sinf(ang);
}

__global__ __launch_bounds__(256) void rope_apply(float* __restrict__ qkv,
    const float* __restrict__ cs, const float* __restrict__ sn)
{
    int idx = blockIdx.x * 256 + threadIdx.x;
    if (idx >= TT * 8 * 32) return;
    int i = idx & 31;
    int h = (idx >> 5) & 7;
    int t = idx >> 8;
    float c = cs[t * 32 + i], s = sn[t * 32 + i];
    size_t base = (size_t)t * 1536 + h * 64 + 2 * i;
    float re = qkv[base], im = qkv[base + 1];
    qkv[base]     = re * c - im * s;
    qkv[base + 1] = re * s + im * c;
    base += 512;
    re = qkv[base]; im = qkv[base + 1];
    qkv[base]     = re * c - im * s;
    qkv[base + 1] = re * s + im * c;
}

__global__ __launch_bounds__(256) void transpose_k(const float* __restrict__ in,
    float* __restrict__ out, int R, int C)
{
    __shared__ float tile[32][33];
    int c0 = blockIdx.x * 32, r0 = blockIdx.y * 32;
    int tx = threadIdx.x & 31, ty = threadIdx.x >> 5;
    for (int dy = ty; dy < 32; dy += 8) {
        int r = r0 + dy, c = c0 + tx;
        tile[dy][tx] = (r < R && c < C) ? in[(size_t)r * C + c] : 0.f;
    }
    __syncthreads();
    for (int dy = ty; dy < 32; dy += 8) {
        int c = c0 + dy, r = r0 + tx;
        if (c < C && r < R) out[(size_t)c * R + r] = tile[tx][dy];
    }
}

__global__ __launch_bounds__(256) void ln_kernel(const float* __restrict__ x,
    const float* __restrict__ w, const float* __restrict__ b, float* __restrict__ y)
{
    int t = blockIdx.x, tid = threadIdx.x;
    const float* xr = x + (size_t)t * 512;
    float v0 = xr[tid], v1 = xr[tid + 256];
    float s = v0 + v1, q = v0 * v0 + v1 * v1;
    for (int off = 32; off; off >>= 1) {
        s += __shfl_down(s, off);
        q += __shfl_down(q, off);
    }
    __shared__ float ss[4], qq[4], mb[2];
    int wid = tid >> 6, lane = tid & 63;
    if (lane == 0) { ss[wid] = s; qq[wid] = q; }
    __syncthreads();
    if (tid == 0) {
        float S = ss[0] + ss[1] + ss[2] + ss[3];
        float Q = qq[0] + qq[1] + qq[2] + qq[3];
        float m = S * (1.f / 512.f);
        float var = Q * (1.f / 512.f) - m * m;
        mb[0] = m;
        mb[1] = rsqrtf(var + 1e-5f);
    }
    __syncthreads();
    float m = mb[0], inv = mb[1];
    y[(size_t)t * 512 + tid]       = (v0 - m) * inv * w[tid] + b[tid];
    y[(size_t)t * 512 + tid + 256] = (v1 - m) * inv * w[tid + 256] + b[tid + 256];
}

__global__ __launch_bounds__(256) void attn_kernel(const float* __restrict__ qkv,
    float* __restrict__ o)
{
    int t = blockIdx.x, h = blockIdx.y, tid = threadIdx.x;
    __shared__ float sq[64];
    __shared__ float sp[256];
    __shared__ float red[256];
    __shared__ float pacc[4][64];
    int klo = t - 249; if (klo < 0) klo = 0;
    int kc = t - klo + 1;
    if (tid < 64) sq[tid] = qkv[(size_t)t * 1536 + h * 64 + tid];
    __syncthreads();
    float sval = -3.0e38f;
    if (tid < kc) {
        const float* kr = qkv + (size_t)(klo + tid) * 1536 + 512 + h * 64;
        float d = 0.f;
#pragma unroll 8
        for (int i = 0; i < 64; i++) d += sq[i] * kr[i];
        sval = d * 0.125f;
    }
    red[tid] = sval;
    __syncthreads();
    for (int s2 = 128; s2 > 0; s2 >>= 1) {
        if (tid < s2) red[tid] = fmaxf(red[tid], red[tid + s2]);
        __syncthreads();
    }
    float m = red[0];
    __syncthreads();
    float p = (tid < kc) ? __expf(sval - m) : 0.f;
    sp[tid] = p;
    red[tid] = p;
    __syncthreads();
    for (int s2 = 128; s2 > 0; s2 >>= 1) {
        if (tid < s2) red[tid] += red[tid + s2];
        __syncthreads();
    }
    float inv = 1.f / red[0];
    int d = tid & 63, g = tid >> 6;
    float a = 0.f;
#pragma unroll 4
    for (int kk = g; kk < kc; kk += 4)
        a += sp[kk] * qkv[(size_t)(klo + kk) * 1536 + 1024 + h * 64 + d];
    pacc[g][d] = a;
    __syncthreads();
    if (tid < 64) {
        float r = (pacc[0][tid] + pacc[1][tid] + pacc[2][tid] + pacc[3][tid]) * inv;
        o[(size_t)t * 512 + h * 64 + tid] = r;
    }
}

// ---------------- MFMA GEMM: C[m,n] = sum_k A[m,k]*Wt[n,k] ----------------
template <int EPI>
__global__ __launch_bounds__(256, 3) void mfma_gemm(const float* __restrict__ A,
    const float* __restrict__ Wt, const float* __restrict__ bias,
    const float* __restrict__ ls, float* __restrict__ C, int M, int N, int K)
{
    constexpr int STR = 72;   // u16 stride (144B, 16B-aligned)
    __shared__ unsigned short sA[128 * STR];
    __shared__ unsigned short sB[128 * STR];
    int tid = threadIdx.x;
    unsigned bxs, bys, bzs; swz_block(bxs, bys, bzs);
    int m0 = bys * 128, n0 = bxs * 128;
    int w = tid >> 6, lane = tid & 63;
    int wm = (w >> 1) * 64, wn = (w & 1) * 64;
    int row15 = lane & 15, q8 = (lane >> 4) * 8;
    int rb = tid >> 3;            // base staging row
    int sg = (tid & 7) * 8;       // k-segment within row
    f32x4 acc[4][4] = {};
    float4 av[8], bv[8];
    const float4 z4 = make_float4(0.f, 0.f, 0.f, 0.f);

    auto prefetch = [&](int k0) {
#pragma unroll
        for (int it = 0; it < 4; it++) {
            int r = rb + it * 32;
            int gm = m0 + r;
            if (gm < M) {
                const float4* p = (const float4*)(A + (size_t)gm * K + k0 + sg);
                av[2 * it] = p[0]; av[2 * it + 1] = p[1];
            } else { av[2 * it] = z4; av[2 * it + 1] = z4; }
            int gn = n0 + r;
            if (gn < N) {
                const float4* p = (const float4*)(Wt + (size_t)gn * K + k0 + sg);
                bv[2 * it] = p[0]; bv[2 * it + 1] = p[1];
            } else { bv[2 * it] = z4; bv[2 * it + 1] = z4; }
        }
    };

    prefetch(0);
    for (int k0 = 0; k0 < K; k0 += 64) {
        __syncthreads();
        // commit to LDS
#pragma unroll
        for (int it = 0; it < 4; it++) {
            int r = rb + it * 32;
            unsigned* d = (unsigned*)&sA[r * STR + sg];
            float4 f0 = av[2 * it], f1 = av[2 * it + 1];
            d[0] = bfu(f0.x) | (bfu(f0.y) << 16); d[1] = bfu(f0.z) | (bfu(f0.w) << 16);
            d[2] = bfu(f1.x) | (bfu(f1.y) << 16); d[3] = bfu(f1.z) | (bfu(f1.w) << 16);
            d = (unsigned*)&sB[r * STR + sg];
            f0 = bv[2 * it]; f1 = bv[2 * it + 1];
            d[0] = bfu(f0.x) | (bfu(f0.y) << 16); d[1] = bfu(f0.z) | (bfu(f0.w) << 16);
            d[2] = bfu(f1.x) | (bfu(f1.y) << 16); d[3] = bfu(f1.z) | (bfu(f1.w) << 16);
        }
        __syncthreads();
        if (k0 + 64 < K) prefetch(k0 + 64);
#pragma unroll
        for (int kk = 0; kk < 64; kk += 32) {
            short8 af[4], bf[4];
#pragma unroll
            for (int f = 0; f < 4; f++) {
                af[f] = *(const short8*)&sA[(wm + f * 16 + row15) * STR + kk + q8];
                bf[f] = *(const short8*)&sB[(wn + f * 16 + row15) * STR + kk + q8];
            }
#pragma unroll
            for (int i = 0; i < 4; i++)
#pragma unroll
                for (int j = 0; j < 4; j++)
                    acc[i][j] = MFMA16(af[i], bf[j], acc[i][j]);
        }
    }
    int rq = (lane >> 4) * 4;
#pragma unroll
    for (int i = 0; i < 4; i++) {
#pragma unroll
        for (int r = 0; r < 4; r++) {
            int m = m0 + wm + i * 16 + rq + r;
            if (m >= M) continue;
#pragma unroll
            for (int j = 0; j < 4; j++) {
                int n = n0 + wn + j * 16 + row15;
                float v = acc[i][j][r] + bias[n];
                size_t idx = (size_t)m * N + n;
                if (EPI == 0) C[idx] = v;
                else if (EPI == 1) C[idx] = 0.5f * v * (1.f + erff(v * 0.70710678118654752f));
                else C[idx] += ls[n] * v;
            }
        }
    }
}

// ---------------- MFMA causal conv (K taps) ----------------
// y[o, t] = b[o] + sum_{ci,j} w[o,ci,j] * f(x[ci, t-(K-1)+j])
// Block tile 64o x 128t; ci-chunks of 32. Two-phase staging, cross-chunk pipeline.
// SHF=0: plain epilogue (opt. ci-split partials via PART).
// SHF=S: transposed-conv epilogue via LDS transpose in TWO 64-col halves; the
//        transpose buffer ALIASES the (dead) staging LDS, keeping LDS ~20 KB.
// launch_bounds(256,3): VGPR budget 170 so prefetch regs NEVER spill (r7 lesson).
template <int K, int SHF, bool ELU_IN, bool ACC, bool PART>
__global__ __launch_bounds__(256, 3) void mfma_conv(
    const float* __restrict__ x, const float* __restrict__ w,
    const float* __restrict__ bias, float* __restrict__ y, float* __restrict__ part,
    unsigned long long pstr,
    int Ci, int Co, int x_str, int Tx, int x_t0, int Ty, int y_t0, int to_lo, int to_hi,
    int sh_lo, int sh_hi, int nz)
{
    constexpr int TL = 128 + K - 1;
    constexpr int SX = 40;  // u16 stride (80B)
    constexpr int SW = 40;
    constexpr int NX = (32 * TL + 255) / 256;  // scalar x elems per thread
    constexpr int NW4 = 2 * K;                 // float4 w loads per thread
    constexpr int SXB = TL * SX;               // u16 counts
    constexpr int SWB = K * 64 * SW;
    static_assert(SHF == 0 || (SXB + SWB) * 2 >= 64 * 66 * 4, "ldsT alias too big");
    __shared__ __align__(16) unsigned short shm[SXB + SWB];
    unsigned short* sX = shm;
    unsigned short* sW = shm + SXB;
    float* ldsT = (float*)shm;                 // SHF>0 only; used after last MFMA
    int tid = threadIdx.x;
    unsigned bxs, bys, bzs; swz_conv(bxs, bys, bzs);
    int co0 = bys * 64;                 // o-row base
    int t_base = to_lo + bxs * 128;
    int zi = (int)bzs;
    int cpz = (Ci / 32) / nz;
    int ci_b = zi * cpz * 32, ci_e = ci_b + cpz * 32;
    int w_id = tid >> 6, lane = tid & 63;
    int wm = (w_id >> 1) * 32, wn = (w_id & 1) * 64;
    int row15 = lane & 15, q8 = (lane >> 4) * 8;
    f32x4 acc[2][4] = {};
    float xv[NX];
    float4 wv4[NW4];
    const float4 z4 = make_float4(0.f, 0.f, 0.f, 0.f);

    auto prefetch = [&](int ci0) {
#pragma unroll
        for (int it = 0; it < NX; it++) {
            int i = tid + it * 256;
            float v = 0.f;
            if (i < 32 * TL) {
                int ci = i / TL, tl = i - ci * TL;
                int gl = t_base - (K - 1) + tl - x_t0;
                if (gl >= 0 && gl < Tx) v = x[(size_t)(ci0 + ci) * x_str + gl];
            }
            xv[it] = v;
        }
#pragma unroll
        for (int it = 0; it < NW4; it++) {
            int i4 = tid + it * 256;
            int co = i4 / (8 * K), r4 = i4 - co * (8 * K);
            wv4[it] = (co0 + co < Co)
                ? *(const float4*)(w + ((size_t)(co0 + co) * Ci + ci0) * K + r4 * 4)
                : z4;
        }
    };
    auto commit = [&]() {
#pragma unroll
        for (int it = 0; it < NX; it++) {
            int i = tid + it * 256;
            if (i < 32 * TL) {
                int ci = i / TL, tl = i - ci * TL;
                float v = xv[it];
                if (ELU_IN) v = v > 0.f ? v : __expf(v) - 1.f;
                sX[tl * SX + ci] = (unsigned short)bfu(v);
            }
        }
#pragma unroll
        for (int it = 0; it < NW4; it++) {
            int i4 = tid + it * 256;
            int co = i4 / (8 * K), r4 = i4 - co * (8 * K);
            float4 f = wv4[it];
#pragma unroll
            for (int e = 0; e < 4; e++) {
                int k = r4 * 4 + e;
                int ci = k / K, j = k - ci * K;
                float fv = (e == 0) ? f.x : (e == 1) ? f.y : (e == 2) ? f.z : f.w;
                sW[(j * 64 + co) * SW + ci] = (unsigned short)bfu(fv);
            }
        }
    };

    prefetch(ci_b);
    for (int ci0 = ci_b; ci0 < ci_e; ci0 += 32) {
        __syncthreads();
        commit();
        __syncthreads();
        if (ci0 + 32 < ci_e) prefetch(ci0 + 32);   // loads fly over the MFMAs below
#pragma unroll
        for (int j = 0; j < K; j++) {
            short8 af[2], bf[4];
#pragma unroll
            for (int f = 0; f < 2; f++)
                af[f] = *(const short8*)&sW[(j * 64 + wm + f * 16 + row15) * SW + q8];
#pragma unroll
            for (int f = 0; f < 4; f++)
                bf[f] = *(const short8*)&sX[(wn + f * 16 + row15 + j) * SX + q8];
#pragma unroll
            for (int i = 0; i < 2; i++)
#pragma unroll
                for (int f = 0; f < 4; f++)
                    acc[i][f] = MFMA16(af[i], bf[f], acc[i][f]);
        }
    }
    int rq = (lane >> 4) * 4;
    if constexpr (SHF > 0) {
        // two halves of 64 t-cols; ldsT aliases the dead staging LDS
        int co_lo = co0 / SHF;
        int cnt = (co0 + 63) / SHF - co_lo + 1;
        int tot = cnt * 64 * SHF;
#pragma unroll
        for (int h = 0; h < 2; h++) {
            __syncthreads();
            if (wn == h * 64) {
#pragma unroll
                for (int i = 0; i < 2; i++) {
#pragma unroll
                    for (int r = 0; r < 4; r++) {
                        int ol = wm + i * 16 + rq + r;
                        float b = bias[(co0 + ol) / SHF];
#pragma unroll
                        for (int f = 0; f < 4; f++)
                            ldsT[ol * 66 + f * 16 + row15] = acc[i][f][r] + b;
                    }
                }
            }
            __syncthreads();
            for (int e = tid; e < tot; e += 256) {
                int cr = e / (64 * SHF), u = e - cr * (64 * SHF);
                int tr = u / SHF, p = u - tr * SHF;
                int co = co_lo + cr;
                int o = co * SHF + p - co0;
                int to = (t_base + h * 64 + tr) * SHF + p;
                if (o >= 0 && o < 64 && to >= sh_lo && to < sh_hi)
                    y[(size_t)co * Ty + (to - y_t0)] = ldsT[o * 66 + tr];
            }
        }
    } else {
#pragma unroll
        for (int i = 0; i < 2; i++) {
#pragma unroll
            for (int r = 0; r < 4; r++) {
                int co = co0 + wm + i * 16 + rq + r;
                if (co >= Co) continue;
                float b = bias[co];
#pragma unroll
                for (int f = 0; f < 4; f++) {
                    int t = t_base + wn + f * 16 + row15;
                    if (t < to_hi) {
                        size_t idx = (size_t)co * Ty + (t - y_t0);
                        if (PART && zi > 0) {
                            part[(size_t)(zi - 1) * pstr + idx] = acc[i][f][r];
                        } else {
                            float v = acc[i][f][r] + b;
                            if (ACC) y[idx] += v; else y[idx] = v;
                        }
                    }
                }
            }
        }
    }
}

// ---------------- final conv (Co=1), fp32 ----------------
__global__ __launch_bounds__(256) void conv7_out_chunk(const float* __restrict__ z4c,
    const float* __restrict__ w, const float* __restrict__ bias,
    float* __restrict__ out, int ext0, int t0, int cnt)
{
    __shared__ float ws_w[64 * 7];
    int tl = blockIdx.x * 256 + threadIdx.x;
    for (int i = threadIdx.x; i < 448; i += 256) ws_w[i] = w[i];
    __syncthreads();
    if (tl >= cnt) return;
    int t = t0 + tl;
    float acc = bias[0];
    for (int ci = 0; ci < 64; ci++) {
        const float* xr = z4c + (size_t)ci * LE_MAX;
#pragma unroll
        for (int j = 0; j < 7; j++) {
            int tg = t - 6 + j;
            float v = 0.f;
            if (tg >= 0) {
                float z = xr[tg - ext0];
                v = z > 0.f ? z : __expf(z) - 1.f;
            }
            acc += ws_w[ci * 7 + j] * v;
        }
    }
    out[t] = acc;
}

// ---------------- host helpers ----------------
template <int K, bool ELU_IN, bool ACC, bool PART>
static void conv_launch(const float* x, const float* w, const float* b, float* y,
    float* part, unsigned long long pstr,
    int Ci, int Co, int x_str, int Tx, int x_t0, int Ty, int y_t0, int to_lo, int to_hi,
    int nz, hipStream_t stream)
{
    dim3 g(cdiv(to_hi - to_lo, 128), cdiv(Co, 64), nz);
    mfma_conv<K, 0, ELU_IN, ACC, PART><<<g, 256, 0, stream>>>(x, w, b, y, part, pstr,
        Ci, Co, x_str, Tx, x_t0, Ty, y_t0, to_lo, to_hi, 0, 0, nz);
}

// transposed conv as K=2 conv over Co*S channels with shuffled epilogue.
template <int S, bool ELU_IN>
static void convtr2_launch(const float* x, const float* wp, const float* b, float* y,
    int Ci, int Co, int Ti, int Ty, int y_t0, int to_lo, int to_hi, hipStream_t stream)
{
    int q_lo = to_lo / S;
    int q_hi = cdiv(to_hi, S);
    dim3 g(cdiv(q_hi - q_lo, 128), (Co * S) / 64, 1);
    mfma_conv<2, S, ELU_IN, false, false><<<g, 256, 0, stream>>>(x, wp, b, y, nullptr, 0,
        Ci, Co * S, Ti, Ti, 0, Ty, y_t0, q_lo, q_hi, to_lo, to_hi, 1);
}

extern "C" void kernel_launch(void* const* d_in, const int* in_sizes, int n_in,
                              void* d_out, int out_size, void* d_ws, size_t ws_size,
                              hipStream_t stream)
{
    const float* latent  = (const float*)d_in[0];
    const float* emb_std = (const float*)d_in[1];
    const float* emb_mean= (const float*)d_in[2];
    const float* quant_w = (const float*)d_in[3];
    const float* quant_b = (const float*)d_in[4];
    const float* up_w    = (const float*)d_in[5];
    const float* up_b    = (const float*)d_in[6];
    const float* n1w     = (const float*)d_in[7];
    const float* n1b     = (const float*)d_in[8];
    const float* ipw     = (const float*)d_in[9];
    const float* ipb     = (const float*)d_in[10];
    const float* opw     = (const float*)d_in[11];
    const float* opb     = (const float*)d_in[12];
    const float* ls1     = (const float*)d_in[13];
    const float* n2w     = (const float*)d_in[14];
    const float* n2b     = (const float*)d_in[15];
    const float* l1w     = (const float*)d_in[16];
    const float* l1b     = (const float*)d_in[17];
    const float* l2w     = (const float*)d_in[18];
    const float* l2b     = (const float*)d_in[19];
    const float* ls2     = (const float*)d_in[20];
    const float* tproj_w = (const float*)d_in[21];
    const float* tproj_b = (const float*)d_in[22];
    const float* dc0_w   = (const float*)d_in[23];
    const float* dc0_b   = (const float*)d_in[24];
    const float* df_w    = (const float*)d_in[49];
    const float* df_b    = (const float*)d_in[50];

    float* W = (float*)d_ws;
    float* OUT = (float*)d_out;

    // ---- frontend ----
    embed_k<<<cdiv(512 * 512, 256), 256, 0, stream>>>(latent, emb_std, emb_mean, W + O_X0);
    conv_launch<1, false, false, true>(W + O_X0, quant_w, quant_b, W + O_XQ,
        W + O_QKV, 262144ULL, 512, 512, 512, 512, 0, 512, 0, 0, 512, 4, stream);
    addp_k<<<cdiv(262144 / 4, 256), 256, 0, stream>>>(W + O_XQ, W + O_QKV, 262144ULL, 3, 262144 / 4);
    wreorder_tr<<<cdiv(1048576, 256), 256, 0, stream>>>(up_w, W + O_QKV, 512, 512, 2, 1048576);
    convtr2_launch<2, false>(W + O_XQ, W + O_QKV, up_b, W + O_XU,
        512, 512, 512, TT, 0, 0, TT, stream);
    transpose_k<<<dim3(cdiv(TT, 32), cdiv(512, 32)), 256, 0, stream>>>(W + O_XU, W + O_Z, 512, TT);
    rope_tables<<<cdiv(TT * 32, 256), 256, 0, stream>>>(W + O_COS, W + O_SIN);

    // ---- transformer ----
    for (int l = 0; l < 8; l++) {
        ln_kernel<<<TT, 256, 0, stream>>>(W + O_Z, n1w + l * 512, n1b + l * 512, W + O_HN);
        mfma_gemm<0><<<dim3(1536 / 128, cdiv(TT, 128)), 256, 0, stream>>>(
            W + O_HN, ipw + (size_t)l * 1536 * 512, ipb + l * 1536, nullptr, W + O_QKV, TT, 1536, 512);
        rope_apply<<<cdiv(TT * 8 * 32, 256), 256, 0, stream>>>(W + O_QKV, W + O_COS, W + O_SIN);
        attn_kernel<<<dim3(TT, 8), 256, 0, stream>>>(W + O_QKV, W + O_AO);
        mfma_gemm<2><<<dim3(512 / 128, cdiv(TT, 128)), 256, 0, stream>>>(
            W + O_AO, opw + (size_t)l * 512 * 512, opb + l * 512, ls1 + l * 512, W + O_Z, TT, 512, 512);
        ln_kernel<<<TT, 256, 0, stream>>>(W + O_Z, n2w + l * 512, n2b + l * 512, W + O_HN);
        mfma_gemm<1><<<dim3(2048 / 128, cdiv(TT, 128)), 256, 0, stream>>>(
            W + O_HN, l1w + (size_t)l * 2048 * 512, l1b + l * 2048, nullptr, W + O_FF, TT, 2048, 512);
        mfma_gemm<2><<<dim3(512 / 128, cdiv(TT, 128)), 256, 0, stream>>>(
            W + O_FF, l2w + (size_t)l * 512 * 2048, l2b + l * 512, ls2 + l * 512, W + O_Z, TT, 512, 2048);
    }

    // ---- back to conv domain ----
    mfma_gemm<0><<<dim3(512 / 128, cdiv(TT, 128)), 256, 0, stream>>>(
        W + O_Z, tproj_w, tproj_b, nullptr, W + O_ZT, TT, 512, 512);
    transpose_k<<<dim3(cdiv(512, 32), cdiv(TT, 32)), 256, 0, stream>>>(W + O_ZT, W + O_ZC, TT, 512);
    conv_launch<7, false, false, true>(W + O_ZC, dc0_w, dc0_b, W + O_D0,
        W + O_FF, 1050624ULL, 512, 1024, TT, TT, 0, TT, 0, 0, TT, 2, stream);
    addp_k<<<cdiv(1050624 / 4, 256), 256, 0, stream>>>(W + O_D0, W + O_FF, 1050624ULL, 1, 1050624 / 4);

    // ---- stage 1: 1024 -> 512, s=8 ----
    {
        const float* tw = (const float*)d_in[25]; const float* tb = (const float*)d_in[26];
        const float* raw = (const float*)d_in[27]; const float* rab = (const float*)d_in[28];
        const float* rbw = (const float*)d_in[29]; const float* rbb = (const float*)d_in[30];
        wreorder_tr<<<cdiv(8388608, 256), 256, 0, stream>>>(tw, W + O_PS1, 1024, 512, 8, 8388608);
        convtr2_launch<8, true>(W + O_D0, W + O_PS1, tb, W + O_Z1,
            1024, 512, TT, T_S1, 0, 0, T_S1, stream);
        conv_launch<3, true, false, true>(W + O_Z1, raw, rab, W + O_V1,
            W + O_PS1, 2103296ULL, 512, 256, T_S1, T_S1, 0, T_S1, 0, 0, T_S1, 2, stream);
        addp_k<<<cdiv(2103296 / 4, 256), 256, 0, stream>>>(W + O_V1, W + O_PS1, 2103296ULL, 1, 2103296 / 4);
        conv_launch<1, true, true, false>(W + O_V1, rbw, rbb, W + O_Z1,
            nullptr, 0ULL, 256, 512, T_S1, T_S1, 0, T_S1, 0, 0, T_S1, 1, stream);
    }
    // ---- stage 2: 512 -> 256, s=6 ----
    {
        const float* tw = (const float*)d_in[31]; const float* tb = (const float*)d_in[32];
        const float* raw = (const float*)d_in[33]; const float* rab = (const float*)d_in[34];
        const float* rbw = (const float*)d_in[35]; const float* rbb = (const float*)d_in[36];
        wreorder_tr<<<cdiv(1572864, 256), 256, 0, stream>>>(tw, W + O_PS1, 512, 256, 6, 1572864);
        convtr2_launch<6, true>(W + O_Z1, W + O_PS1, tb, W + O_Z2,
            512, 256, T_S1, T_S2, 0, 0, T_S2, stream);
        conv_launch<3, true, false, false>(W + O_Z2, raw, rab, W + O_V2,
            nullptr, 0ULL, 256, 128, T_S2, T_S2, 0, T_S2, 0, 0, T_S2, 1, stream);
        conv_launch<1, true, true, false>(W + O_V2, rbw, rbb, W + O_Z2,
            nullptr, 0ULL, 128, 256, T_S2, T_S2, 0, T_S2, 0, 0, T_S2, 1, stream);
    }
    // ---- stage 3: 256 -> 128, s=5 ----
    {
        const float* tw = (const float*)d_in[37]; const float* tb = (const float*)d_in[38];
        const float* raw = (const float*)d_in[39]; const float* rab = (const float*)d_in[40];
        const float* rbw = (const float*)d_in[41]; const float* rbb = (const float*)d_in[42];
        wreorder_tr<<<cdiv(327680, 256), 256, 0, stream>>>(tw, W + O_WS3, 256, 128, 5, 327680);
        convtr2_launch<5, true>(W + O_Z2, W + O_WS3, tb, W + O_Z3,
            256, 128, T_S2, T_S3, 0, 0, T_S3, stream);
        conv_launch<3, true, false, false>(W + O_Z3, raw, rab, W + O_V3,
            nullptr, 0ULL, 128, 64, T_S3, T_S3, 0, T_S3, 0, 0, T_S3, 1, stream);
        conv_launch<1, true, true, false>(W + O_V3, rbw, rbb, W + O_Z3,
            nullptr, 0ULL, 64, 128, T_S3, T_S3, 0, T_S3, 0, 0, T_S3, 1, stream);
    }
    // ---- stage 4 (128 -> 64, s=4) + final conv: temporally chunked ----
    {
        const float* tw = (const float*)d_in[43]; const float* tb = (const float*)d_in[44];
        const float* raw = (const float*)d_in[45]; const float* rab = (const float*)d_in[46];
        const float* rbw = (const float*)d_in[47]; const float* rbb = (const float*)d_in[48];
        wreorder_tr<<<cdiv(65536, 256), 256, 0, stream>>>(tw, W + O_WS4, 128, 64, 4, 65536);
        for (int c = 0; c < NCH; c++) {
            int t0 = c * LC;
            int ext0 = (c == 0) ? 0 : t0 - 8;
            int Le = t0 + LC - ext0;
            int vlo = (c == 0) ? 0 : ext0 + 2;
            convtr2_launch<4, true>(W + O_Z3, W + O_WS4, tb, W + O_Z4C,
                128, 64, T_S3, LE_MAX, ext0, ext0, ext0 + Le, stream);
            conv_launch<3, true, false, false>(W + O_Z4C, raw, rab, W + O_VAC,
                nullptr, 0ULL, 64, 32, LE_MAX, Le, ext0, LE_MAX, ext0, vlo, ext0 + Le, 1, stream);
            conv_launch<1, true, true, false>(W + O_VAC, rbw, rbb, W + O_Z4C,
                nullptr, 0ULL, 32, 64, LE_MAX, Le, ext0, LE_MAX, ext0, vlo, ext0 + Le, 1, stream);
            conv7_out_chunk<<<dim3(cdiv(LC, 256), 1), 256, 0, stream>>>(
                W + O_Z4C, df_w, df_b, OUT, ext0, t0, LC);
        }
    }
}

// Round 9
// 5441.708 us; speedup vs baseline: 1.3802x; 1.2745x over previous
//
#include <hip/hip_runtime.h>
#include <math.h>

typedef __attribute__((ext_vector_type(8))) short short8;
typedef __attribute__((ext_vector_type(4))) float f32x4;

#define MFMA16(a, b, c) __builtin_amdgcn_mfma_f32_16x16x32_bf16((a), (b), (c), 0, 0, 0)

__device__ __forceinline__ unsigned bfu(float f) {
    unsigned u = __float_as_uint(f);
    return (u + 0x7fffu + ((u >> 16) & 1u)) >> 16;   // RNE fp32->bf16
}
__device__ __forceinline__ float bf2f(unsigned short u) {
    return __uint_as_float((unsigned)u << 16);
}

// Bijective XCD chunking for ANY nb: hardware assigns XCD = d%8 (round-robin);
// remap so each XCD owns a CONTIGUOUS logical range.
__device__ __forceinline__ unsigned xcd_chunk(unsigned d, unsigned nb) {
    unsigned q = nb >> 3, r = nb & 7u;
    unsigned x = d & 7u, i = d >> 3;
    return (x < r) ? x * (q + 1) + i : r * (q + 1) + (x - r) * q + i;
}

// GEMM swizzle: bx-fastest (consecutive logical ids share by = A-row panel).
__device__ __forceinline__ void swz_block(unsigned& bx, unsigned& by, unsigned& bz) {
    unsigned gx = gridDim.x, gy = gridDim.y, gz = gridDim.z;
    unsigned nb = gx * gy * gz;
    unsigned d = xcd_chunk(blockIdx.x + gx * (blockIdx.y + gy * blockIdx.z), nb);
    bx = d % gx;
    unsigned r = d / gx;
    by = r % gy;
    bz = r / gy;
}

// Conv swizzle: by-fastest (consecutive logical ids share bx = x tile); with
// xcd_chunk, all gy sharers of one x tile land on the SAME XCD's L2.
__device__ __forceinline__ void swz_conv(unsigned& bx, unsigned& by, unsigned& bz) {
    unsigned gx = gridDim.x, gy = gridDim.y, gz = gridDim.z;
    unsigned nb = gx * gy * gz;
    unsigned d = xcd_chunk(blockIdx.x + gx * (blockIdx.y + gy * blockIdx.z), nb);
    by = d % gy;
    unsigned r = d / gy;
    bx = r % gx;
    bz = r / gx;
}

// ---------------- constants ----------------
static constexpr int TT   = 1026;
static constexpr int T_S1 = 8216;
static constexpr int T_S2 = 49302;
static constexpr int T_S3 = 246515;
static constexpr int T_S4 = 986064;

static constexpr int NCH    = 8;
static constexpr int LC     = T_S4 / NCH;        // 123258
static constexpr int LE_MAX = LC + 8;

// workspace offsets (floats).
static constexpr size_t O_X0  = 0;
static constexpr size_t O_XQ  = 262144;
static constexpr size_t O_XU  = 524288;
static constexpr size_t O_Z   = 1049600;
static constexpr size_t O_HN  = 1574912;
static constexpr size_t O_QKV = 2100224;   // also: quant partials, up-convtr w'
static constexpr size_t O_AO  = 3676160;
static constexpr size_t O_FF  = 4201472;   // also: dc0 partial
static constexpr size_t O_COS = 6302720;
static constexpr size_t O_SIN = 6335552;
static constexpr size_t O_ZT  = 6368384;
static constexpr size_t O_ZC  = 6893696;
static constexpr size_t O_D0  = 7419008;
static constexpr size_t O_Z1  = 8469632;
static constexpr size_t O_V1  = 12676224;
static constexpr size_t O_PS1 = 16000000;  // gemm K-split partials, s1/s2 convtr w', s1-conv3 partial
static constexpr size_t O_Z2  = 31553920;
static constexpr size_t O_V2  = 0;         // bf16 now (u16 elements at this float offset)
static constexpr size_t O_Z3  = 0;
static constexpr size_t O_V3  = 31553920;  // bf16
static constexpr size_t O_Z4C = 31553920;
static constexpr size_t O_VAC = 39442944;  // bf16
static constexpr size_t O_WS4 = 43388928;  // stage-4 convtr w' (65,536)
static constexpr size_t O_WS3 = 44176256;  // stage-3 convtr w' (327,680)

static constexpr unsigned long long GP_STR = 525312ULL;  // 1026*512 gemm partial stride

static inline int cdiv(int a, int b) { return (a + b - 1) / b; }

// ---------------- partial reduce: y[i] += sum_z p[i + z*pstr] ----------------
__global__ __launch_bounds__(256) void addp_k(float* __restrict__ y,
    const float* __restrict__ p, unsigned long long pstr, int np, int n4)
{
    int i = blockIdx.x * 256 + threadIdx.x;
    if (i >= n4) return;
    float4 s = ((float4*)y)[i];
    for (int z = 0; z < np; z++) {
        float4 q = ((const float4*)(p + (size_t)z * pstr))[i];
        s.x += q.x; s.y += q.y; s.z += q.z; s.w += q.w;
    }
    ((float4*)y)[i] = s;
}

// ---------------- gemm K-split combine: C += ls*(sum_z part + b) ----------------
__global__ __launch_bounds__(256) void gemm_comb2(float* __restrict__ C,
    const float* __restrict__ part, unsigned long long pstr, int np,
    const float* __restrict__ bias, const float* __restrict__ ls, int N4, int n4tot)
{
    int i = blockIdx.x * 256 + threadIdx.x;
    if (i >= n4tot) return;
    float4 s = make_float4(0.f, 0.f, 0.f, 0.f);
    for (int z = 0; z < np; z++) {
        float4 q = ((const float4*)(part + (size_t)z * pstr))[i];
        s.x += q.x; s.y += q.y; s.z += q.z; s.w += q.w;
    }
    int nb = i % N4;
    float4 b4 = ((const float4*)bias)[nb];
    float4 l4 = ((const float4*)ls)[nb];
    float4 c = ((float4*)C)[i];
    c.x += l4.x * (s.x + b4.x);
    c.y += l4.y * (s.y + b4.y);
    c.z += l4.z * (s.z + b4.z);
    c.w += l4.w * (s.w + b4.w);
    ((float4*)C)[i] = c;
}

// ---------------- convtr weight reorder ----------------
__global__ __launch_bounds__(256) void wreorder_tr(const float* __restrict__ w,
    float* __restrict__ wp, int Ci, int Co, int S, int n)
{
    int i = blockIdx.x * 256 + threadIdx.x;
    if (i >= n) return;
    int o = i / (Ci * 2), r = i - o * (Ci * 2);
    int ci = r >> 1, j = r & 1;
    int co = o / S, p = o - co * S;
    wp[i] = w[((size_t)ci * Co + co) * (2 * S) + (1 - j) * S + p];
}

// ---------------- elementwise / small fp32 kernels ----------------
__global__ __launch_bounds__(256) void embed_k(const float* __restrict__ lat,
    const float* __restrict__ sd, const float* __restrict__ mn, float* __restrict__ y)
{
    int i = blockIdx.x * 256 + threadIdx.x;
    if (i >= 512 * 512) return;
    int c = i >> 9;
    y[i] = lat[i] * sd[c] + mn[c];
}

__global__ __launch_bounds__(256) void rope_tables(float* __restrict__ cs, float* __restrict__ sn)
{
    int idx = blockIdx.x * 256 + threadIdx.x;
    if (idx >= TT * 32) return;
    int i = idx & 31;
    int t = idx >> 5;
    float fr = expf(-(float)i * (logf(10000.f) / 32.f));
    float ang = (float)t * fr;
    cs[idx] = cosf(ang);
    sn[idx] = sinf(ang);
}

__global__ __launch_bounds__(256) void rope_apply(float* __restrict__ qkv,
    const float* __restrict__ cs, const float* __restrict__ sn)
{
    int idx = blockIdx.x * 256 + threadIdx.x;
    if (idx >= TT * 8 * 32) return;
    int i = idx & 31;
    int h = (idx >> 5) & 7;
    int t = idx >> 8;
    float c = cs[t * 32 + i], s = sn[t * 32 + i];
    size_t base = (size_t)t * 1536 + h * 64 + 2 * i;
    float re = qkv[base], im = qkv[base + 1];
    qkv[base]     = re * c - im * s;
    qkv[base + 1] = re * s + im * c;
    base += 512;
    re = qkv[base]; im = qkv[base + 1];
    qkv[base]     = re * c - im * s;
    qkv[base + 1] = re * s + im * c;
}

__global__ __launch_bounds__(256) void transpose_k(const float* __restrict__ in,
    float* __restrict__ out, int R, int C)
{
    __shared__ float tile[32][33];
    int c0 = blockIdx.x * 32, r0 = blockIdx.y * 32;
    int tx = threadIdx.x & 31, ty = threadIdx.x >> 5;
    for (int dy = ty; dy < 32; dy += 8) {
        int r = r0 + dy, c = c0 + tx;
        tile[dy][tx] = (r < R && c < C) ? in[(size_t)r * C + c] : 0.f;
    }
    __syncthreads();
    for (int dy = ty; dy < 32; dy += 8) {
        int c = c0 + dy, r = r0 + tx;
        if (c < C && r < R) out[(size_t)c * R + r] = tile[tx][dy];
    }
}

__global__ __launch_bounds__(256) void ln_kernel(const float* __restrict__ x,
    const float* __restrict__ w, const float* __restrict__ b, float* __restrict__ y)
{
    int t = blockIdx.x, tid = threadIdx.x;
    const float* xr = x + (size_t)t * 512;
    float v0 = xr[tid], v1 = xr[tid + 256];
    float s = v0 + v1, q = v0 * v0 + v1 * v1;
    for (int off = 32; off; off >>= 1) {
        s += __shfl_down(s, off);
        q += __shfl_down(q, off);
    }
    __shared__ float ss[4], qq[4], mb[2];
    int wid = tid >> 6, lane = tid & 63;
    if (lane == 0) { ss[wid] = s; qq[wid] = q; }
    __syncthreads();
    if (tid == 0) {
        float S = ss[0] + ss[1] + ss[2] + ss[3];
        float Q = qq[0] + qq[1] + qq[2] + qq[3];
        float m = S * (1.f / 512.f);
        float var = Q * (1.f / 512.f) - m * m;
        mb[0] = m;
        mb[1] = rsqrtf(var + 1e-5f);
    }
    __syncthreads();
    float m = mb[0], inv = mb[1];
    y[(size_t)t * 512 + tid]       = (v0 - m) * inv * w[tid] + b[tid];
    y[(size_t)t * 512 + tid + 256] = (v1 - m) * inv * w[tid + 256] + b[tid + 256];
}

__global__ __launch_bounds__(256) void attn_kernel(const float* __restrict__ qkv,
    float* __restrict__ o)
{
    int t = blockIdx.x, h = blockIdx.y, tid = threadIdx.x;
    __shared__ float sq[64];
    __shared__ float sp[256];
    __shared__ float red[256];
    __shared__ float pacc[4][64];
    int klo = t - 249; if (klo < 0) klo = 0;
    int kc = t - klo + 1;
    if (tid < 64) sq[tid] = qkv[(size_t)t * 1536 + h * 64 + tid];
    __syncthreads();
    float sval = -3.0e38f;
    if (tid < kc) {
        const float* kr = qkv + (size_t)(klo + tid) * 1536 + 512 + h * 64;
        float d = 0.f;
#pragma unroll 8
        for (int i = 0; i < 64; i++) d += sq[i] * kr[i];
        sval = d * 0.125f;
    }
    red[tid] = sval;
    __syncthreads();
    for (int s2 = 128; s2 > 0; s2 >>= 1) {
        if (tid < s2) red[tid] = fmaxf(red[tid], red[tid + s2]);
        __syncthreads();
    }
    float m = red[0];
    __syncthreads();
    float p = (tid < kc) ? __expf(sval - m) : 0.f;
    sp[tid] = p;
    red[tid] = p;
    __syncthreads();
    for (int s2 = 128; s2 > 0; s2 >>= 1) {
        if (tid < s2) red[tid] += red[tid + s2];
        __syncthreads();
    }
    float inv = 1.f / red[0];
    int d = tid & 63, g = tid >> 6;
    float a = 0.f;
#pragma unroll 4
    for (int kk = g; kk < kc; kk += 4)
        a += sp[kk] * qkv[(size_t)(klo + kk) * 1536 + 1024 + h * 64 + d];
    pacc[g][d] = a;
    __syncthreads();
    if (tid < 64) {
        float r = (pacc[0][tid] + pacc[1][tid] + pacc[2][tid] + pacc[3][tid]) * inv;
        o[(size_t)t * 512 + h * 64 + tid] = r;
    }
}

// ---------------- MFMA GEMM: C[m,n] = sum_k A[m,k]*Wt[n,k] ----------------
// GPART: K split over grid.z; each slice writes RAW acc to part[z*pstr+...];
// epilogue (bias/ls) applied later by gemm_comb2.
template <int EPI, bool GPART>
__global__ __launch_bounds__(256, 3) void mfma_gemm(const float* __restrict__ A,
    const float* __restrict__ Wt, const float* __restrict__ bias,
    const float* __restrict__ ls, float* __restrict__ C, int M, int N, int K,
    float* __restrict__ part, unsigned long long pstr, int nz)
{
    constexpr int STR = 72;   // u16 stride (144B, 16B-aligned)
    __shared__ unsigned short sA[128 * STR];
    __shared__ unsigned short sB[128 * STR];
    int tid = threadIdx.x;
    unsigned bxs, bys, bzs; swz_block(bxs, bys, bzs);
    int m0 = bys * 128, n0 = bxs * 128;
    int kb = (int)bzs * (K / nz), ke = kb + K / nz;
    int w = tid >> 6, lane = tid & 63;
    int wm = (w >> 1) * 64, wn = (w & 1) * 64;
    int row15 = lane & 15, q8 = (lane >> 4) * 8;
    int rb = tid >> 3;            // base staging row
    int sg = (tid & 7) * 8;       // k-segment within row
    f32x4 acc[4][4] = {};
    float4 av[8], bv[8];
    const float4 z4 = make_float4(0.f, 0.f, 0.f, 0.f);

    auto prefetch = [&](int k0) {
#pragma unroll
        for (int it = 0; it < 4; it++) {
            int r = rb + it * 32;
            int gm = m0 + r;
            if (gm < M) {
                const float4* p = (const float4*)(A + (size_t)gm * K + k0 + sg);
                av[2 * it] = p[0]; av[2 * it + 1] = p[1];
            } else { av[2 * it] = z4; av[2 * it + 1] = z4; }
            int gn = n0 + r;
            if (gn < N) {
                const float4* p = (const float4*)(Wt + (size_t)gn * K + k0 + sg);
                bv[2 * it] = p[0]; bv[2 * it + 1] = p[1];
            } else { bv[2 * it] = z4; bv[2 * it + 1] = z4; }
        }
    };

    prefetch(kb);
    for (int k0 = kb; k0 < ke; k0 += 64) {
        __syncthreads();
        // commit to LDS
#pragma unroll
        for (int it = 0; it < 4; it++) {
            int r = rb + it * 32;
            unsigned* d = (unsigned*)&sA[r * STR + sg];
            float4 f0 = av[2 * it], f1 = av[2 * it + 1];
            d[0] = bfu(f0.x) | (bfu(f0.y) << 16); d[1] = bfu(f0.z) | (bfu(f0.w) << 16);
            d[2] = bfu(f1.x) | (bfu(f1.y) << 16); d[3] = bfu(f1.z) | (bfu(f1.w) << 16);
            d = (unsigned*)&sB[r * STR + sg];
            f0 = bv[2 * it]; f1 = bv[2 * it + 1];
            d[0] = bfu(f0.x) | (bfu(f0.y) << 16); d[1] = bfu(f0.z) | (bfu(f0.w) << 16);
            d[2] = bfu(f1.x) | (bfu(f1.y) << 16); d[3] = bfu(f1.z) | (bfu(f1.w) << 16);
        }
        __syncthreads();
        if (k0 + 64 < ke) prefetch(k0 + 64);
#pragma unroll
        for (int kk = 0; kk < 64; kk += 32) {
            short8 af[4], bf[4];
#pragma unroll
            for (int f = 0; f < 4; f++) {
                af[f] = *(const short8*)&sA[(wm + f * 16 + row15) * STR + kk + q8];
                bf[f] = *(const short8*)&sB[(wn + f * 16 + row15) * STR + kk + q8];
            }
#pragma unroll
            for (int i = 0; i < 4; i++)
#pragma unroll
                for (int j = 0; j < 4; j++)
                    acc[i][j] = MFMA16(af[i], bf[j], acc[i][j]);
        }
    }
    int rq = (lane >> 4) * 4;
#pragma unroll
    for (int i = 0; i < 4; i++) {
#pragma unroll
        for (int r = 0; r < 4; r++) {
            int m = m0 + wm + i * 16 + rq + r;
            if (m >= M) continue;
#pragma unroll
            for (int j = 0; j < 4; j++) {
                int n = n0 + wn + j * 16 + row15;
                size_t idx = (size_t)m * N + n;
                if (GPART) {
                    part[(size_t)bzs * pstr + idx] = acc[i][j][r];
                } else {
                    float v = acc[i][j][r] + bias[n];
                    if (EPI == 0) C[idx] = v;
                    else if (EPI == 1) C[idx] = 0.5f * v * (1.f + erff(v * 0.70710678118654752f));
                    else C[idx] += ls[n] * v;
                }
            }
        }
    }
}

// ---------------- MFMA causal conv (K taps) ----------------
// y[o, t] = b[o] + sum_{ci,j} w[o,ci,j] * f(x[ci, t-(K-1)+j])
// XBF: x buffer is bf16 (u16); OBF: y written as bf16 (plain epilogue only).
// SHF=S: transposed-conv epilogue via LDS transpose (aliases staging LDS).
template <int K, int SHF, bool ELU_IN, bool ACC, bool PART, bool XBF, bool OBF>
__global__ __launch_bounds__(256, 3) void mfma_conv(
    const float* __restrict__ x, const float* __restrict__ w,
    const float* __restrict__ bias, float* __restrict__ y, float* __restrict__ part,
    unsigned long long pstr,
    int Ci, int Co, int x_str, int Tx, int x_t0, int Ty, int y_t0, int to_lo, int to_hi,
    int sh_lo, int sh_hi, int nz)
{
    constexpr int TL = 128 + K - 1;
    constexpr int SX = 40;  // u16 stride (80B)
    constexpr int SW = 40;
    constexpr int NX = (32 * TL + 255) / 256;  // scalar x elems per thread
    constexpr int NW4 = 2 * K;                 // float4 w loads per thread
    constexpr int SXB = TL * SX;               // u16 counts
    constexpr int SWB = K * 64 * SW;
    static_assert(SHF == 0 || (SXB + SWB) * 2 >= 64 * 66 * 4, "ldsT alias too big");
    __shared__ __align__(16) unsigned short shm[SXB + SWB];
    unsigned short* sX = shm;
    unsigned short* sW = shm + SXB;
    float* ldsT = (float*)shm;                 // SHF>0 only; used after last MFMA
    int tid = threadIdx.x;
    unsigned bxs, bys, bzs; swz_conv(bxs, bys, bzs);
    int co0 = bys * 64;                 // o-row base
    int t_base = to_lo + bxs * 128;
    int zi = (int)bzs;
    int cpz = (Ci / 32) / nz;
    int ci_b = zi * cpz * 32, ci_e = ci_b + cpz * 32;
    int w_id = tid >> 6, lane = tid & 63;
    int wm = (w_id >> 1) * 32, wn = (w_id & 1) * 64;
    int row15 = lane & 15, q8 = (lane >> 4) * 8;
    f32x4 acc[2][4] = {};
    float xv[XBF ? 1 : NX];
    unsigned short xvu[XBF ? NX : 1];
    float4 wv4[NW4];
    const float4 z4 = make_float4(0.f, 0.f, 0.f, 0.f);
    const unsigned short* xu = (const unsigned short*)x;

    auto prefetch = [&](int ci0) {
#pragma unroll
        for (int it = 0; it < NX; it++) {
            int i = tid + it * 256;
            if (i < 32 * TL) {
                int ci = i / TL, tl = i - ci * TL;
                int gl = t_base - (K - 1) + tl - x_t0;
                bool ok = (gl >= 0 && gl < Tx);
                if (XBF) xvu[it] = ok ? xu[(size_t)(ci0 + ci) * x_str + gl] : (unsigned short)0;
                else     xv[it]  = ok ? x[(size_t)(ci0 + ci) * x_str + gl] : 0.f;
            } else {
                if (XBF) xvu[it] = 0; else xv[it] = 0.f;
            }
        }
#pragma unroll
        for (int it = 0; it < NW4; it++) {
            int i4 = tid + it * 256;
            int co = i4 / (8 * K), r4 = i4 - co * (8 * K);
            wv4[it] = (co0 + co < Co)
                ? *(const float4*)(w + ((size_t)(co0 + co) * Ci + ci0) * K + r4 * 4)
                : z4;
        }
    };
    auto commit = [&]() {
#pragma unroll
        for (int it = 0; it < NX; it++) {
            int i = tid + it * 256;
            if (i < 32 * TL) {
                int ci = i / TL, tl = i - ci * TL;
                float v = XBF ? bf2f(xvu[it]) : xv[it];
                if (ELU_IN) v = v > 0.f ? v : __expf(v) - 1.f;
                sX[tl * SX + ci] = (unsigned short)bfu(v);
            }
        }
#pragma unroll
        for (int it = 0; it < NW4; it++) {
            int i4 = tid + it * 256;
            int co = i4 / (8 * K), r4 = i4 - co * (8 * K);
            float4 f = wv4[it];
#pragma unroll
            for (int e = 0; e < 4; e++) {
                int k = r4 * 4 + e;
                int ci = k / K, j = k - ci * K;
                float fv = (e == 0) ? f.x : (e == 1) ? f.y : (e == 2) ? f.z : f.w;
                sW[(j * 64 + co) * SW + ci] = (unsigned short)bfu(fv);
            }
        }
    };

    prefetch(ci_b);
    for (int ci0 = ci_b; ci0 < ci_e; ci0 += 32) {
        __syncthreads();
        commit();
        __syncthreads();
        if (ci0 + 32 < ci_e) prefetch(ci0 + 32);   // loads fly over the MFMAs below
#pragma unroll
        for (int j = 0; j < K; j++) {
            short8 af[2], bf[4];
#pragma unroll
            for (int f = 0; f < 2; f++)
                af[f] = *(const short8*)&sW[(j * 64 + wm + f * 16 + row15) * SW + q8];
#pragma unroll
            for (int f = 0; f < 4; f++)
                bf[f] = *(const short8*)&sX[(wn + f * 16 + row15 + j) * SX + q8];
#pragma unroll
            for (int i = 0; i < 2; i++)
#pragma unroll
                for (int f = 0; f < 4; f++)
                    acc[i][f] = MFMA16(af[i], bf[f], acc[i][f]);
        }
    }
    int rq = (lane >> 4) * 4;
    if constexpr (SHF > 0) {
        // two halves of 64 t-cols; ldsT aliases the dead staging LDS
        int co_lo = co0 / SHF;
        int cnt = (co0 + 63) / SHF - co_lo + 1;
        int tot = cnt * 64 * SHF;
#pragma unroll
        for (int h = 0; h < 2; h++) {
            __syncthreads();
            if (wn == h * 64) {
#pragma unroll
                for (int i = 0; i < 2; i++) {
#pragma unroll
                    for (int r = 0; r < 4; r++) {
                        int ol = wm + i * 16 + rq + r;
                        float b = bias[(co0 + ol) / SHF];
#pragma unroll
                        for (int f = 0; f < 4; f++)
                            ldsT[ol * 66 + f * 16 + row15] = acc[i][f][r] + b;
                    }
                }
            }
            __syncthreads();
            for (int e = tid; e < tot; e += 256) {
                int cr = e / (64 * SHF), u = e - cr * (64 * SHF);
                int tr = u / SHF, p = u - tr * SHF;
                int co = co_lo + cr;
                int o = co * SHF + p - co0;
                int to = (t_base + h * 64 + tr) * SHF + p;
                if (o >= 0 && o < 64 && to >= sh_lo && to < sh_hi)
                    y[(size_t)co * Ty + (to - y_t0)] = ldsT[o * 66 + tr];
            }
        }
    } else {
#pragma unroll
        for (int i = 0; i < 2; i++) {
#pragma unroll
            for (int r = 0; r < 4; r++) {
                int co = co0 + wm + i * 16 + rq + r;
                if (co >= Co) continue;
                float b = bias[co];
#pragma unroll
                for (int f = 0; f < 4; f++) {
                    int t = t_base + wn + f * 16 + row15;
                    if (t < to_hi) {
                        size_t idx = (size_t)co * Ty + (t - y_t0);
                        if (PART && zi > 0) {
                            part[(size_t)(zi - 1) * pstr + idx] = acc[i][f][r];
                        } else {
                            float v = acc[i][f][r] + b;
                            if (OBF) {
                                ((unsigned short*)y)[idx] = (unsigned short)bfu(v);
                            } else {
                                if (ACC) y[idx] += v; else y[idx] = v;
                            }
                        }
                    }
                }
            }
        }
    }
}

// ---------------- final conv (Co=1), fp32 ----------------
__global__ __launch_bounds__(256) void conv7_out_chunk(const float* __restrict__ z4c,
    const float* __restrict__ w, const float* __restrict__ bias,
    float* __restrict__ out, int ext0, int t0, int cnt)
{
    __shared__ float ws_w[64 * 7];
    int tl = blockIdx.x * 256 + threadIdx.x;
    for (int i = threadIdx.x; i < 448; i += 256) ws_w[i] = w[i];
    __syncthreads();
    if (tl >= cnt) return;
    int t = t0 + tl;
    float acc = bias[0];
    for (int ci = 0; ci < 64; ci++) {
        const float* xr = z4c + (size_t)ci * LE_MAX;
#pragma unroll
        for (int j = 0; j < 7; j++) {
            int tg = t - 6 + j;
            float v = 0.f;
            if (tg >= 0) {
                float z = xr[tg - ext0];
                v = z > 0.f ? z : __expf(z) - 1.f;
            }
            acc += ws_w[ci * 7 + j] * v;
        }
    }
    out[t] = acc;
}

// ---------------- host helpers ----------------
template <int K, bool ELU_IN, bool ACC, bool PART, bool XBF = false, bool OBF = false>
static void conv_launch(const float* x, const float* w, const float* b, float* y,
    float* part, unsigned long long pstr,
    int Ci, int Co, int x_str, int Tx, int x_t0, int Ty, int y_t0, int to_lo, int to_hi,
    int nz, hipStream_t stream)
{
    dim3 g(cdiv(to_hi - to_lo, 128), cdiv(Co, 64), nz);
    mfma_conv<K, 0, ELU_IN, ACC, PART, XBF, OBF><<<g, 256, 0, stream>>>(x, w, b, y, part, pstr,
        Ci, Co, x_str, Tx, x_t0, Ty, y_t0, to_lo, to_hi, 0, 0, nz);
}

// transposed conv as K=2 conv over Co*S channels with shuffled epilogue.
template <int S, bool ELU_IN>
static void convtr2_launch(const float* x, const float* wp, const float* b, float* y,
    int Ci, int Co, int Ti, int Ty, int y_t0, int to_lo, int to_hi, hipStream_t stream)
{
    int q_lo = to_lo / S;
    int q_hi = cdiv(to_hi, S);
    dim3 g(cdiv(q_hi - q_lo, 128), (Co * S) / 64, 1);
    mfma_conv<2, S, ELU_IN, false, false, false, false><<<g, 256, 0, stream>>>(x, wp, b, y, nullptr, 0,
        Ci, Co * S, Ti, Ti, 0, Ty, y_t0, q_lo, q_hi, to_lo, to_hi, 1);
}

extern "C" void kernel_launch(void* const* d_in, const int* in_sizes, int n_in,
                              void* d_out, int out_size, void* d_ws, size_t ws_size,
                              hipStream_t stream)
{
    const float* latent  = (const float*)d_in[0];
    const float* emb_std = (const float*)d_in[1];
    const float* emb_mean= (const float*)d_in[2];
    const float* quant_w = (const float*)d_in[3];
    const float* quant_b = (const float*)d_in[4];
    const float* up_w    = (const float*)d_in[5];
    const float* up_b    = (const float*)d_in[6];
    const float* n1w     = (const float*)d_in[7];
    const float* n1b     = (const float*)d_in[8];
    const float* ipw     = (const float*)d_in[9];
    const float* ipb     = (const float*)d_in[10];
    const float* opw     = (const float*)d_in[11];
    const float* opb     = (const float*)d_in[12];
    const float* ls1     = (const float*)d_in[13];
    const float* n2w     = (const float*)d_in[14];
    const float* n2b     = (const float*)d_in[15];
    const float* l1w     = (const float*)d_in[16];
    const float* l1b     = (const float*)d_in[17];
    const float* l2w     = (const float*)d_in[18];
    const float* l2b     = (const float*)d_in[19];
    const float* ls2     = (const float*)d_in[20];
    const float* tproj_w = (const float*)d_in[21];
    const float* tproj_b = (const float*)d_in[22];
    const float* dc0_w   = (const float*)d_in[23];
    const float* dc0_b   = (const float*)d_in[24];
    const float* df_w    = (const float*)d_in[49];
    const float* df_b    = (const float*)d_in[50];

    float* W = (float*)d_ws;
    float* OUT = (float*)d_out;

    // ---- frontend ----
    embed_k<<<cdiv(512 * 512, 256), 256, 0, stream>>>(latent, emb_std, emb_mean, W + O_X0);
    conv_launch<1, false, false, true>(W + O_X0, quant_w, quant_b, W + O_XQ,
        W + O_QKV, 262144ULL, 512, 512, 512, 512, 0, 512, 0, 0, 512, 4, stream);
    addp_k<<<cdiv(262144 / 4, 256), 256, 0, stream>>>(W + O_XQ, W + O_QKV, 262144ULL, 3, 262144 / 4);
    wreorder_tr<<<cdiv(1048576, 256), 256, 0, stream>>>(up_w, W + O_QKV, 512, 512, 2, 1048576);
    convtr2_launch<2, false>(W + O_XQ, W + O_QKV, up_b, W + O_XU,
        512, 512, 512, TT, 0, 0, TT, stream);
    transpose_k<<<dim3(cdiv(TT, 32), cdiv(512, 32)), 256, 0, stream>>>(W + O_XU, W + O_Z, 512, TT);
    rope_tables<<<cdiv(TT * 32, 256), 256, 0, stream>>>(W + O_COS, W + O_SIN);

    // ---- transformer ----
    for (int l = 0; l < 8; l++) {
        ln_kernel<<<TT, 256, 0, stream>>>(W + O_Z, n1w + l * 512, n1b + l * 512, W + O_HN);
        mfma_gemm<0, false><<<dim3(1536 / 128, cdiv(TT, 128)), 256, 0, stream>>>(
            W + O_HN, ipw + (size_t)l * 1536 * 512, ipb + l * 1536, nullptr, W + O_QKV, TT, 1536, 512,
            nullptr, 0ULL, 1);
        rope_apply<<<cdiv(TT * 8 * 32, 256), 256, 0, stream>>>(W + O_QKV, W + O_COS, W + O_SIN);
        attn_kernel<<<dim3(TT, 8), 256, 0, stream>>>(W + O_QKV, W + O_AO);
        // op proj: K-split x2, combine applies C += ls1*(acc+b)
        mfma_gemm<2, true><<<dim3(512 / 128, cdiv(TT, 128), 2), 256, 0, stream>>>(
            W + O_AO, opw + (size_t)l * 512 * 512, opb + l * 512, ls1 + l * 512, W + O_Z, TT, 512, 512,
            W + O_PS1, GP_STR, 2);
        gemm_comb2<<<cdiv((int)(GP_STR / 4), 256), 256, 0, stream>>>(
            W + O_Z, W + O_PS1, GP_STR, 2, opb + l * 512, ls1 + l * 512, 512 / 4, (int)(GP_STR / 4));
        ln_kernel<<<TT, 256, 0, stream>>>(W + O_Z, n2w + l * 512, n2b + l * 512, W + O_HN);
        mfma_gemm<1, false><<<dim3(2048 / 128, cdiv(TT, 128)), 256, 0, stream>>>(
            W + O_HN, l1w + (size_t)l * 2048 * 512, l1b + l * 2048, nullptr, W + O_FF, TT, 2048, 512,
            nullptr, 0ULL, 1);
        // ff2: K-split x4, combine applies C += ls2*(acc+b)
        mfma_gemm<2, true><<<dim3(512 / 128, cdiv(TT, 128), 4), 256, 0, stream>>>(
            W + O_FF, l2w + (size_t)l * 512 * 2048, l2b + l * 512, ls2 + l * 512, W + O_Z, TT, 512, 2048,
            W + O_PS1, GP_STR, 4);
        gemm_comb2<<<cdiv((int)(GP_STR / 4), 256), 256, 0, stream>>>(
            W + O_Z, W + O_PS1, GP_STR, 4, l2b + l * 512, ls2 + l * 512, 512 / 4, (int)(GP_STR / 4));
    }

    // ---- back to conv domain ----
    mfma_gemm<0, false><<<dim3(512 / 128, cdiv(TT, 128)), 256, 0, stream>>>(
        W + O_Z, tproj_w, tproj_b, nullptr, W + O_ZT, TT, 512, 512, nullptr, 0ULL, 1);
    transpose_k<<<dim3(cdiv(512, 32), cdiv(TT, 32)), 256, 0, stream>>>(W + O_ZT, W + O_ZC, TT, 512);
    conv_launch<7, false, false, true>(W + O_ZC, dc0_w, dc0_b, W + O_D0,
        W + O_FF, 1050624ULL, 512, 1024, TT, TT, 0, TT, 0, 0, TT, 2, stream);
    addp_k<<<cdiv(1050624 / 4, 256), 256, 0, stream>>>(W + O_D0, W + O_FF, 1050624ULL, 1, 1050624 / 4);

    // ---- stage 1: 1024 -> 512, s=8 ----
    {
        const float* tw = (const float*)d_in[25]; const float* tb = (const float*)d_in[26];
        const float* raw = (const float*)d_in[27]; const float* rab = (const float*)d_in[28];
        const float* rbw = (const float*)d_in[29]; const float* rbb = (const float*)d_in[30];
        wreorder_tr<<<cdiv(8388608, 256), 256, 0, stream>>>(tw, W + O_PS1, 1024, 512, 8, 8388608);
        convtr2_launch<8, true>(W + O_D0, W + O_PS1, tb, W + O_Z1,
            1024, 512, TT, T_S1, 0, 0, T_S1, stream);
        conv_launch<3, true, false, true>(W + O_Z1, raw, rab, W + O_V1,
            W + O_PS1, 2103296ULL, 512, 256, T_S1, T_S1, 0, T_S1, 0, 0, T_S1, 2, stream);
        addp_k<<<cdiv(2103296 / 4, 256), 256, 0, stream>>>(W + O_V1, W + O_PS1, 2103296ULL, 1, 2103296 / 4);
        conv_launch<1, true, true, false>(W + O_V1, rbw, rbb, W + O_Z1,
            nullptr, 0ULL, 256, 512, T_S1, T_S1, 0, T_S1, 0, 0, T_S1, 1, stream);
    }
    // ---- stage 2: 512 -> 256, s=6 ---- (V2 bf16)
    {
        const float* tw = (const float*)d_in[31]; const float* tb = (const float*)d_in[32];
        const float* raw = (const float*)d_in[33]; const float* rab = (const float*)d_in[34];
        const float* rbw = (const float*)d_in[35]; const float* rbb = (const float*)d_in[36];
        wreorder_tr<<<cdiv(1572864, 256), 256, 0, stream>>>(tw, W + O_PS1, 512, 256, 6, 1572864);
        convtr2_launch<6, true>(W + O_Z1, W + O_PS1, tb, W + O_Z2,
            512, 256, T_S1, T_S2, 0, 0, T_S2, stream);
        conv_launch<3, true, false, false, false, true>(W + O_Z2, raw, rab, W + O_V2,
            nullptr, 0ULL, 256, 128, T_S2, T_S2, 0, T_S2, 0, 0, T_S2, 1, stream);
        conv_launch<1, true, true, false, true, false>(W + O_V2, rbw, rbb, W + O_Z2,
            nullptr, 0ULL, 128, 256, T_S2, T_S2, 0, T_S2, 0, 0, T_S2, 1, stream);
    }
    // ---- stage 3: 256 -> 128, s=5 ---- (V3 bf16)
    {
        const float* tw = (const float*)d_in[37]; const float* tb = (const float*)d_in[38];
        const float* raw = (const float*)d_in[39]; const float* rab = (const float*)d_in[40];
        const float* rbw = (const float*)d_in[41]; const float* rbb = (const float*)d_in[42];
        wreorder_tr<<<cdiv(327680, 256), 256, 0, stream>>>(tw, W + O_WS3, 256, 128, 5, 327680);
        convtr2_launch<5, true>(W + O_Z2, W + O_WS3, tb, W + O_Z3,
            256, 128, T_S2, T_S3, 0, 0, T_S3, stream);
        conv_launch<3, true, false, false, false, true>(W + O_Z3, raw, rab, W + O_V3,
            nullptr, 0ULL, 128, 64, T_S3, T_S3, 0, T_S3, 0, 0, T_S3, 1, stream);
        conv_launch<1, true, true, false, true, false>(W + O_V3, rbw, rbb, W + O_Z3,
            nullptr, 0ULL, 64, 128, T_S3, T_S3, 0, T_S3, 0, 0, T_S3, 1, stream);
    }
    // ---- stage 4 (128 -> 64, s=4) + final conv: temporally chunked ---- (VAC bf16)
    {
        const float* tw = (const float*)d_in[43]; const float* tb = (const float*)d_in[44];
        const float* raw = (const float*)d_in[45]; const float* rab = (const float*)d_in[46];
        const float* rbw = (const float*)d_in[47]; const float* rbb = (const float*)d_in[48];
        wreorder_tr<<<cdiv(65536, 256), 256, 0, stream>>>(tw, W + O_WS4, 128, 64, 4, 65536);
        for (int c = 0; c < NCH; c++) {
            int t0 = c * LC;
            int ext0 = (c == 0) ? 0 : t0 - 8;
            int Le = t0 + LC - ext0;
            int vlo = (c == 0) ? 0 : ext0 + 2;
            convtr2_launch<4, true>(W + O_Z3, W + O_WS4, tb, W + O_Z4C,
                128, 64, T_S3, LE_MAX, ext0, ext0, ext0 + Le, stream);
            conv_launch<3, true, false, false, false, true>(W + O_Z4C, raw, rab, W + O_VAC,
                nullptr, 0ULL, 64, 32, LE_MAX, Le, ext0, LE_MAX, ext0, vlo, ext0 + Le, 1, stream);
            conv_launch<1, true, true, false, true, false>(W + O_VAC, rbw, rbb, W + O_Z4C,
                nullptr, 0ULL, 32, 64, LE_MAX, Le, ext0, LE_MAX, ext0, vlo, ext0 + Le, 1, stream);
            conv7_out_chunk<<<dim3(cdiv(LC, 256), 1), 256, 0, stream>>>(
                W + O_Z4C, df_w, df_b, OUT, ext0, t0, LC);
        }
    }
}